// Round 4
// baseline (7784.509 us; speedup 1.0000x reference)
//
#include <hip/hip_runtime.h>
#include <cstdio>
#include <cstdint>

#define TT    20
#define BATCH 512
#define HID   1024
#define G4    4096
#define BT    (BATCH * TT)   // 10240
#define NCLS  200

typedef unsigned short u16;
typedef __attribute__((ext_vector_type(8))) short short8;   // 8 bf16 (4 VGPRs)
typedef __attribute__((ext_vector_type(4))) float f32x4;

__device__ __forceinline__ float sigf(float x) { return 1.0f / (1.0f + __expf(-x)); }

__device__ __forceinline__ u16 f2bf(float x) {
    unsigned u = __float_as_uint(x);
    u += 0x7FFFu + ((u >> 16) & 1u);           // RNE
    return (u16)(u >> 16);
}
__device__ __forceinline__ float bf2f(u16 b) { return __uint_as_float(((unsigned)b) << 16); }
__device__ __forceinline__ void split2(float x, u16& h, u16& l) {
    h = f2bf(x);
    l = f2bf(x - bf2f(h));
}

// async 16B global -> LDS (global_load_lds_dwordx4); LDS dest must be linear in lane order
__device__ __forceinline__ void gld16(const u16* g, u16* l) {
    __builtin_amdgcn_global_load_lds(
        (const __attribute__((address_space(1))) void*)g,
        (__attribute__((address_space(3))) void*)l, 16, 0, 0);
}

// vectorized fp32 -> (hi, lo) bf16 split, float4 per thread
__global__ void split4_kernel(const float* __restrict__ x, u16* __restrict__ hi,
                              u16* __restrict__ lo, int n4)
{
    const int stride = gridDim.x * blockDim.x;
    for (int i = blockIdx.x * blockDim.x + threadIdx.x; i < n4; i += stride) {
        const float4 v = ((const float4*)x)[i];
        u16 h0,l0,h1,l1,h2,l2,h3,l3;
        split2(v.x,h0,l0); split2(v.y,h1,l1); split2(v.z,h2,l2); split2(v.w,h3,l3);
        uint2 hp, lp;
        hp.x = (unsigned)h0 | ((unsigned)h1 << 16); hp.y = (unsigned)h2 | ((unsigned)h3 << 16);
        lp.x = (unsigned)l0 | ((unsigned)l1 << 16); lp.y = (unsigned)l2 | ((unsigned)l3 << 16);
        ((uint2*)hi)[i] = hp; ((uint2*)lo)[i] = lp;
    }
}

// ---------------------------------------------------------------------------
// bf16x3 MFMA GEMM (m97 structure): C[M,N] = A[M,K] @ W[N,K]^T + b1 + b2
// A, W pre-split (hi/lo bf16). 128x128 tile, BK=32, 256 thr = 4 waves (2x2).
// global_load_lds staging, [4][128][8] LDS, term-major MFMA. M,N%128==0, K%32==0.
// 1D grid with bijective XCD swizzle; nbx = M/128 (nwg must be %8==0).
// ---------------------------------------------------------------------------
template<bool EMIT>
__launch_bounds__(256)
__global__ void mfma_gemm(const u16* __restrict__ Ah, const u16* __restrict__ Al,
                          const u16* __restrict__ Wh, const u16* __restrict__ Wl,
                          const float* __restrict__ b1, const float* __restrict__ b2,
                          float* __restrict__ Cf, u16* __restrict__ Ch, u16* __restrict__ Cl,
                          int M, int N, int K, int nbx)
{
    __shared__ u16 sAh[4][128][8]; __shared__ u16 sAl[4][128][8];
    __shared__ u16 sWh[4][128][8]; __shared__ u16 sWl[4][128][8];
    const int tid = threadIdx.x, lane = tid & 63, w = tid >> 6;
    const int wr = w >> 1, wc = w & 1;

    // bijective XCD swizzle (nwg % 8 == 0 for all shapes used)
    const int nwg = gridDim.x;
    const int cpx = nwg >> 3;
    const int lg = (blockIdx.x & 7) * cpx + (blockIdx.x >> 3);
    const int m0 = (lg % nbx) * 128;
    const int n0 = (lg / nbx) * 128;

    const u16* Ah0 = Ah + (size_t)m0 * K;
    const u16* Al0 = Al + (size_t)m0 * K;
    const u16* Wh0 = Wh + (size_t)n0 * K;
    const u16* Wl0 = Wl + (size_t)n0 * K;

    f32x4 acc[4][4];
#pragma unroll
    for (int i = 0; i < 4; ++i)
#pragma unroll
        for (int j = 0; j < 4; ++j) acc[i][j] = f32x4{0.f, 0.f, 0.f, 0.f};

    const int u1 = tid, u2 = tid + 256;
    const size_t go1 = (size_t)(u1 & 127) * K + (u1 >> 7) * 8;
    const size_t go2 = (size_t)(u2 & 127) * K + (u2 >> 7) * 8;
    u16* const l1 = (u16*)sAh + (size_t)u1 * 8;  // same flat offset for all 4 arrays
    u16* const l2 = (u16*)sAh + (size_t)u2 * 8;
    const size_t dAl = (u16*)sAl - (u16*)sAh;
    const size_t dWh = (u16*)sWh - (u16*)sAh;
    const size_t dWl = (u16*)sWl - (u16*)sAh;

    for (int k0 = 0; k0 < K; k0 += 32) {
        gld16(Ah0 + go1 + k0, l1);        gld16(Ah0 + go2 + k0, l2);
        gld16(Al0 + go1 + k0, l1 + dAl);  gld16(Al0 + go2 + k0, l2 + dAl);
        gld16(Wh0 + go1 + k0, l1 + dWh);  gld16(Wh0 + go2 + k0, l2 + dWh);
        gld16(Wl0 + go1 + k0, l1 + dWl);  gld16(Wl0 + go2 + k0, l2 + dWl);
        __syncthreads();

        const int kb = lane >> 4, rr = lane & 15;
        short8 Avh[4], Avl[4], Wvh[4], Wvl[4];
#pragma unroll
        for (int i = 0; i < 4; ++i) {
            Avh[i] = *(const short8*)&sAh[kb][wr * 64 + i * 16 + rr][0];
            Avl[i] = *(const short8*)&sAl[kb][wr * 64 + i * 16 + rr][0];
            Wvh[i] = *(const short8*)&sWh[kb][wc * 64 + i * 16 + rr][0];
            Wvl[i] = *(const short8*)&sWl[kb][wc * 64 + i * 16 + rr][0];
        }
        // term-major: dependency distance 16 between reuses of the same acc
#pragma unroll
        for (int i = 0; i < 4; ++i)
#pragma unroll
            for (int j = 0; j < 4; ++j)
                acc[i][j] = __builtin_amdgcn_mfma_f32_16x16x32_bf16(Avh[i], Wvh[j], acc[i][j], 0, 0, 0);
#pragma unroll
        for (int i = 0; i < 4; ++i)
#pragma unroll
            for (int j = 0; j < 4; ++j)
                acc[i][j] = __builtin_amdgcn_mfma_f32_16x16x32_bf16(Avh[i], Wvl[j], acc[i][j], 0, 0, 0);
#pragma unroll
        for (int i = 0; i < 4; ++i)
#pragma unroll
            for (int j = 0; j < 4; ++j)
                acc[i][j] = __builtin_amdgcn_mfma_f32_16x16x32_bf16(Avl[i], Wvh[j], acc[i][j], 0, 0, 0);
        __syncthreads();
    }

    const int rr = lane & 15, rg = lane >> 4;
#pragma unroll
    for (int j = 0; j < 4; ++j) {
        const int col = n0 + wc * 64 + j * 16 + rr;
        const float bias = (b1 ? b1[col] : 0.f) + (b2 ? b2[col] : 0.f);
#pragma unroll
        for (int i = 0; i < 4; ++i) {
#pragma unroll
            for (int q = 0; q < 4; ++q) {
                const int row = m0 + wr * 64 + i * 16 + rg * 4 + q;
                const float v = acc[i][j][q] + bias;
                if (EMIT) {
                    u16 h, l; split2(v, h, l);
                    Ch[(size_t)row * N + col] = h;
                    Cl[(size_t)row * N + col] = l;
                } else {
                    Cf[(size_t)row * N + col] = v;
                }
            }
        }
    }
}

// ---------------------------------------------------------------------------
// MFMA LSTM step: gates = h_in @ Whh^T + G, then cell update.
// Block: 128 batch x 32 j x 4 gates (=128 gate-cols). 4 waves 2x2; wave =
// 64 rows x (16 j x 4 gates). W staged gate-interleaved via per-lane global
// source addresses (global_load_lds keeps LDS linear). Lane owns all 4 gates
// of its (b, j) -> in-register cell update.
// ---------------------------------------------------------------------------
struct Step2 {
    const u16* WhhH[2]; const u16* WhhL[2];
    const float* G[2];
    const u16* hinH[2]; const u16* hinL[2];
    u16* houtH[2]; u16* houtL[2];
    float* c[2]; float* hfin[2];
    int t[2];
};

__launch_bounds__(256)
__global__ void lstm_step_mfma(Step2 a)
{
    const int l = blockIdx.z;
    __shared__ u16 sAh[4][128][8]; __shared__ u16 sAl[4][128][8];
    __shared__ u16 sWh[4][128][8]; __shared__ u16 sWl[4][128][8];
    const int tid = threadIdx.x, lane = tid & 63, w = tid >> 6;
    const int wr = w >> 1, wc = w & 1;
    const int m0 = blockIdx.x * 128;
    const int j0 = blockIdx.y * 32;

    const u16* hH = a.hinH[l]; const u16* hL = a.hinL[l];
    const u16* WH = a.WhhH[l]; const u16* WL = a.WhhL[l];

    f32x4 acc[4][4];   // [row-frag i][gate g]
#pragma unroll
    for (int i = 0; i < 4; ++i)
#pragma unroll
        for (int g = 0; g < 4; ++g) acc[i][g] = f32x4{0.f, 0.f, 0.f, 0.f};

    const int u1 = tid, u2 = tid + 256;
    // A: LDS row r holds h row m0+r
    const size_t goA1 = (size_t)(m0 + (u1 & 127)) * HID + (u1 >> 7) * 8;
    const size_t goA2 = (size_t)(m0 + (u2 & 127)) * HID + (u2 >> 7) * 8;
    // W: LDS row r holds Whh row gate*1024 + j0 + (r>>6)*16 + (r&15), gate=(r>>4)&3
    const int r1 = u1 & 127, r2 = u2 & 127;
    const size_t goW1 = (size_t)(((r1 >> 4) & 3) * HID + j0 + (r1 >> 6) * 16 + (r1 & 15)) * HID + (u1 >> 7) * 8;
    const size_t goW2 = (size_t)(((r2 >> 4) & 3) * HID + j0 + (r2 >> 6) * 16 + (r2 & 15)) * HID + (u2 >> 7) * 8;
    u16* const l1 = (u16*)sAh + (size_t)u1 * 8;
    u16* const l2 = (u16*)sAh + (size_t)u2 * 8;
    const size_t dAl = (u16*)sAl - (u16*)sAh;
    const size_t dWh = (u16*)sWh - (u16*)sAh;
    const size_t dWl = (u16*)sWl - (u16*)sAh;

    for (int k0 = 0; k0 < HID; k0 += 32) {
        gld16(hH + goA1 + k0, l1);        gld16(hH + goA2 + k0, l2);
        gld16(hL + goA1 + k0, l1 + dAl);  gld16(hL + goA2 + k0, l2 + dAl);
        gld16(WH + goW1 + k0, l1 + dWh);  gld16(WH + goW2 + k0, l2 + dWh);
        gld16(WL + goW1 + k0, l1 + dWl);  gld16(WL + goW2 + k0, l2 + dWl);
        __syncthreads();

        const int kb = lane >> 4, rr = lane & 15;
        short8 Avh[4], Avl[4], Wvh[4], Wvl[4];
#pragma unroll
        for (int i = 0; i < 4; ++i) {
            Avh[i] = *(const short8*)&sAh[kb][wr * 64 + i * 16 + rr][0];
            Avl[i] = *(const short8*)&sAl[kb][wr * 64 + i * 16 + rr][0];
            Wvh[i] = *(const short8*)&sWh[kb][wc * 64 + i * 16 + rr][0];
            Wvl[i] = *(const short8*)&sWl[kb][wc * 64 + i * 16 + rr][0];
        }
#pragma unroll
        for (int i = 0; i < 4; ++i)
#pragma unroll
            for (int g = 0; g < 4; ++g)
                acc[i][g] = __builtin_amdgcn_mfma_f32_16x16x32_bf16(Avh[i], Wvh[g], acc[i][g], 0, 0, 0);
#pragma unroll
        for (int i = 0; i < 4; ++i)
#pragma unroll
            for (int g = 0; g < 4; ++g)
                acc[i][g] = __builtin_amdgcn_mfma_f32_16x16x32_bf16(Avh[i], Wvl[g], acc[i][g], 0, 0, 0);
#pragma unroll
        for (int i = 0; i < 4; ++i)
#pragma unroll
            for (int g = 0; g < 4; ++g)
                acc[i][g] = __builtin_amdgcn_mfma_f32_16x16x32_bf16(Avl[i], Wvh[g], acc[i][g], 0, 0, 0);
        __syncthreads();
    }

    const int rr = lane & 15, rg = lane >> 4;
    const int j = j0 + wc * 16 + rr;
    const int t = a.t[l];
    const float* __restrict__ G = a.G[l];
    float* __restrict__ cb = a.c[l];
    float* __restrict__ hf = a.hfin[l];
    u16* __restrict__ hoH = a.houtH[l];
    u16* __restrict__ hoL = a.houtL[l];
#pragma unroll
    for (int i = 0; i < 4; ++i) {
#pragma unroll
        for (int q = 0; q < 4; ++q) {
            const int b = m0 + wr * 64 + i * 16 + rg * 4 + q;
            const float* gp = G + ((size_t)b * TT + t) * G4 + j;
            const float pi = acc[i][0][q] + gp[0];
            const float pf = acc[i][1][q] + gp[1024];
            const float pg = acc[i][2][q] + gp[2048];
            const float po = acc[i][3][q] + gp[3072];
            const size_t idx = (size_t)b * HID + j;
            const float cn = sigf(pf) * cb[idx] + sigf(pi) * tanhf(pg);
            cb[idx] = cn;
            const float h = sigf(po) * tanhf(cn);
            hf[idx] = h;
            u16 hh, hl; split2(h, hh, hl);
            hoH[idx] = hh; hoL[idx] = hl;
        }
    }
}

// fused[b, n] = prod over streams of concat(h_fwd, h_rev); hfin layout [l][b][j]
__global__ void fuse_mul_kernel(const float* __restrict__ hfin, float* __restrict__ fused)
{
    const int idx = blockIdx.x * blockDim.x + threadIdx.x;
    if (idx >= BATCH * 2 * HID) return;
    const int b = idx >> 11;
    const int n = idx & 2047;
    const int half = n >> 10;
    const int j = n & 1023;
    const size_t o = (size_t)b * HID + j;
    const size_t S = (size_t)BATCH * HID;
    fused[idx] = hfin[(size_t)(0 + half) * S + o] *
                 hfin[(size_t)(2 + half) * S + o] *
                 hfin[(size_t)(4 + half) * S + o];
}

// fp32 vector GEMM for the small classifier (N=200): C = A@W^T + b
__launch_bounds__(256)
__global__ void gemm_bias_kernel(const float* __restrict__ A, const float* __restrict__ W,
                                 const float* __restrict__ b1,
                                 float* __restrict__ C, int M, int N, int K)
{
    __shared__ float As[16][68];
    __shared__ float Ws[16][68];
    const int tid = threadIdx.x;
    const int tx = tid & 15, ty = tid >> 4;
    const int m0 = blockIdx.x * 64;
    const int n0 = blockIdx.y * 64;
    const int lr = tid >> 2;
    const int lk = (tid & 3) << 2;
    const bool mok = (m0 + lr < M);
    const bool nok = (n0 + lr < N);
    const float* Arow = A + (size_t)(m0 + lr) * K + lk;
    const float* Wrow = W + (size_t)(n0 + lr) * K + lk;
    float acc[4][4] = {};

    for (int k0 = 0; k0 < K; k0 += 16) {
        float4 av = make_float4(0.f, 0.f, 0.f, 0.f);
        float4 wv = make_float4(0.f, 0.f, 0.f, 0.f);
        if (mok) av = *(const float4*)(Arow + k0);
        if (nok) wv = *(const float4*)(Wrow + k0);
        As[lk + 0][lr] = av.x; As[lk + 1][lr] = av.y; As[lk + 2][lr] = av.z; As[lk + 3][lr] = av.w;
        Ws[lk + 0][lr] = wv.x; Ws[lk + 1][lr] = wv.y; Ws[lk + 2][lr] = wv.z; Ws[lk + 3][lr] = wv.w;
        __syncthreads();
#pragma unroll
        for (int k = 0; k < 16; ++k) {
            const float4 a = *(const float4*)&As[k][ty << 2];
            const float4 ww = *(const float4*)&Ws[k][tx << 2];
            const float a4[4] = {a.x, a.y, a.z, a.w};
            const float w4[4] = {ww.x, ww.y, ww.z, ww.w};
#pragma unroll
            for (int i = 0; i < 4; ++i)
#pragma unroll
                for (int j = 0; j < 4; ++j)
                    acc[i][j] = fmaf(a4[i], w4[j], acc[i][j]);
        }
        __syncthreads();
    }

#pragma unroll
    for (int i = 0; i < 4; ++i) {
        const int m = m0 + (ty << 2) + i;
        if (m >= M) continue;
#pragma unroll
        for (int j = 0; j < 4; ++j) {
            const int n = n0 + (tx << 2) + j;
            if (n >= N) continue;
            C[(size_t)m * N + n] = acc[i][j] + (b1 ? b1[n] : 0.f);
        }
    }
}

extern "C" void kernel_launch(void* const* d_in, const int* in_sizes, int n_in,
                              void* d_out, int out_size, void* d_ws, size_t ws_size,
                              hipStream_t stream)
{
    const float* resnet   = (const float*)d_in[0];
    const float* c3d      = (const float*)d_in[1];
    const float* audio    = (const float*)d_in[2];
    const float* W_audio  = (const float*)d_in[3];
    const float* b_audio  = (const float*)d_in[4];
    const float* W_resnet = (const float*)d_in[5];
    const float* b_resnet = (const float*)d_in[6];
    const float* W_c3d    = (const float*)d_in[7];
    const float* b_c3d    = (const float*)d_in[8];
    const float* Wih[6]; const float* Whh[6]; const float* bih[6]; const float* bhh[6];
    for (int l = 0; l < 6; ++l) {
        Wih[l] = (const float*)d_in[9 + 4 * l];
        Whh[l] = (const float*)d_in[10 + 4 * l];
        bih[l] = (const float*)d_in[11 + 4 * l];
        bhh[l] = (const float*)d_in[12 + 4 * l];
    }
    const float* W_out = (const float*)d_in[33];
    const float* b_out = (const float*)d_in[34];
    float* out = (float*)d_out;

    // stream order: 0=audio(K=128), 1=resnet(K=2048), 2=c3d(K=4096)
    const float* feat[3] = { audio, resnet, c3d };
    const float* fb[3]   = { b_audio, b_resnet, b_c3d };
    const int    fK[3]   = { 128, 2048, 4096 };

    // ---- workspace carve (bytes); reuse feat/proj/weight buffers per stream ----
    char* p = (char*)d_ws;
    char* pend = p + ws_size;
    auto alloc = [&](size_t bytes) -> void* {
        void* q = p; p += (bytes + 255) & ~(size_t)255; return q;
    };
    const size_t FW = (size_t)1024 * (128 + 2048 + 4096);
    u16* featH = (u16*)alloc((size_t)BT * 4096 * 2);          // max-K stream
    u16* featL = (u16*)alloc((size_t)BT * 4096 * 2);
    u16* fwH   = (u16*)alloc(FW * 2);
    u16* fwL   = (u16*)alloc(FW * 2);
    u16* wihH  = (u16*)alloc((size_t)2 * G4 * HID * 2);
    u16* wihL  = (u16*)alloc((size_t)2 * G4 * HID * 2);
    u16* whhH  = (u16*)alloc((size_t)2 * G4 * HID * 2);
    u16* whhL  = (u16*)alloc((size_t)2 * G4 * HID * 2);
    u16* projH = (u16*)alloc((size_t)BT * HID * 2);           // current stream only
    u16* projL = (u16*)alloc((size_t)BT * HID * 2);
    float* G   = (float*)alloc((size_t)2 * BT * G4 * 4);
    u16* hAH = (u16*)alloc((size_t)2 * BATCH * HID * 2);
    u16* hAL = (u16*)alloc((size_t)2 * BATCH * HID * 2);
    u16* hBH = (u16*)alloc((size_t)2 * BATCH * HID * 2);
    u16* hBL = (u16*)alloc((size_t)2 * BATCH * HID * 2);
    float* cb    = (float*)alloc((size_t)2 * BATCH * HID * 4);
    float* hfin  = (float*)alloc((size_t)6 * BATCH * HID * 4);
    float* fused = (float*)alloc((size_t)BATCH * 2 * HID * 4);
    if (p > pend) {
        fprintf(stderr, "kernel_launch: ws too small: need %zu have %zu\n",
                (size_t)(p - (char*)d_ws), ws_size);
        return;
    }

    const dim3 blk(256);
    const size_t fwOff[3] = { 0, (size_t)1024 * 128, (size_t)1024 * 128 + (size_t)1024 * 2048 };

    // 0. split the three projection weight matrices (once)
    for (int st = 0; st < 3; ++st) {
        const int n4 = (1024 * fK[st]) / 4;
        split4_kernel<<<dim3(min(2048, (n4 + 255) / 256)), blk, 0, stream>>>(
            (st == 0 ? W_audio : st == 1 ? W_resnet : W_c3d), fwH + fwOff[st], fwL + fwOff[st], n4);
    }

    // per stream: split feats -> proj -> split lstm weights -> G gemms -> recurrence
    for (int st = 0; st < 3; ++st) {
        const int K = fK[st];
        {   // split features
            const int n4 = (BT * K) / 4;
            split4_kernel<<<dim3(2048), blk, 0, stream>>>(feat[st], featH, featL, n4);
        }
        {   // projection: (BT x K) @ (1024 x K)^T -> split proj
            mfma_gemm<true><<<dim3((BT / 128) * (HID / 128)), blk, 0, stream>>>(
                featH, featL, fwH + fwOff[st], fwL + fwOff[st], fb[st], nullptr,
                nullptr, projH, projL, BT, HID, K, BT / 128);
        }
        for (int d = 0; d < 2; ++d) {
            const int l = st * 2 + d;
            const size_t woff = (size_t)d * G4 * HID;
            const int n4 = (G4 * HID) / 4;
            split4_kernel<<<dim3(2048), blk, 0, stream>>>(Wih[l], wihH + woff, wihL + woff, n4);
            split4_kernel<<<dim3(2048), blk, 0, stream>>>(Whh[l], whhH + woff, whhL + woff, n4);
            mfma_gemm<false><<<dim3((BT / 128) * (G4 / 128)), blk, 0, stream>>>(
                projH, projL, wihH + woff, wihL + woff, bih[l], bhh[l],
                G + (size_t)d * BT * G4, nullptr, nullptr, BT, G4, HID, BT / 128);
        }

        hipMemsetAsync(hAH, 0, (size_t)2 * BATCH * HID * 2, stream);
        hipMemsetAsync(hAL, 0, (size_t)2 * BATCH * HID * 2, stream);
        hipMemsetAsync(cb,  0, (size_t)2 * BATCH * HID * 4, stream);

        for (int s = 0; s < TT; ++s) {
            Step2 a;
            u16* inH  = (s & 1) ? hBH : hAH;  u16* inL  = (s & 1) ? hBL : hAL;
            u16* outH = (s & 1) ? hAH : hBH;  u16* outL = (s & 1) ? hAL : hBL;
            for (int d = 0; d < 2; ++d) {
                const int l = st * 2 + d;
                const size_t woff = (size_t)d * G4 * HID;
                const size_t hoff = (size_t)d * BATCH * HID;
                a.WhhH[d] = whhH + woff; a.WhhL[d] = whhL + woff;
                a.G[d]    = G + (size_t)d * BT * G4;
                a.hinH[d] = inH + hoff;  a.hinL[d] = inL + hoff;
                a.houtH[d] = outH + hoff; a.houtL[d] = outL + hoff;
                a.c[d]    = cb + hoff;
                a.hfin[d] = hfin + (size_t)l * BATCH * HID;
                a.t[d]    = d ? (TT - 1 - s) : s;
            }
            lstm_step_mfma<<<dim3(BATCH / 128, HID / 32, 2), blk, 0, stream>>>(a);
        }
    }

    // fused elementwise product
    fuse_mul_kernel<<<dim3((BATCH * 2 * HID) / 256), blk, 0, stream>>>(hfin, fused);

    // classifier (small, fp32 vector path)
    gemm_bias_kernel<<<dim3(BATCH / 64, (NCLS + 63) / 64), blk, 0, stream>>>(
        fused, W_out, b_out, out, BATCH, NCLS, 2 * HID);
}

// Round 6
// 5389.316 us; speedup vs baseline: 1.4444x; 1.4444x over previous
//
#include <hip/hip_runtime.h>
#include <cstdio>
#include <cstdint>

#define TT    20
#define BATCH 512
#define HID   1024
#define G4    4096
#define BT    (BATCH * TT)  // 10240
#define NCLS  200

typedef unsigned short u16;
typedef __attribute__((ext_vector_type(8))) short short8;   // 8 bf16 (4 VGPRs)
typedef __attribute__((ext_vector_type(4))) float f32x4;

__device__ __forceinline__ float sigf(float x) { return 1.0f / (1.0f + __expf(-x)); }

__device__ __forceinline__ u16 f2bf(float x) {
    unsigned u = __float_as_uint(x);
    u += 0x7FFFu + ((u >> 16) & 1u);           // RNE
    return (u16)(u >> 16);
}
__device__ __forceinline__ float bf2f(u16 b) { return __uint_as_float(((unsigned)b) << 16); }
__device__ __forceinline__ void split2(float x, u16& h, u16& l) {
    h = f2bf(x);
    l = f2bf(x - bf2f(h));
}

// async 16B global -> LDS; LDS dest must be linear in lane order
__device__ __forceinline__ void gld16(const u16* g, u16* l) {
    __builtin_amdgcn_global_load_lds(
        (const __attribute__((address_space(1))) void*)g,
        (__attribute__((address_space(3))) void*)l, 16, 0, 0);
}

// vectorized fp32 -> (hi, lo) bf16 split, float4 per thread
__global__ void split4_kernel(const float* __restrict__ x, u16* __restrict__ hi,
                              u16* __restrict__ lo, int n4)
{
    const int stride = gridDim.x * blockDim.x;
    for (int i = blockIdx.x * blockDim.x + threadIdx.x; i < n4; i += stride) {
        const float4 v = ((const float4*)x)[i];
        u16 h0,l0,h1,l1,h2,l2,h3,l3;
        split2(v.x,h0,l0); split2(v.y,h1,l1); split2(v.z,h2,l2); split2(v.w,h3,l3);
        uint2 hp, lp;
        hp.x = (unsigned)h0 | ((unsigned)h1 << 16); hp.y = (unsigned)h2 | ((unsigned)h3 << 16);
        lp.x = (unsigned)l0 | ((unsigned)l1 << 16); lp.y = (unsigned)l2 | ((unsigned)l3 << 16);
        ((uint2*)hi)[i] = hp; ((uint2*)lo)[i] = lp;
    }
}

// vectorized fp32 -> plain bf16 convert (for Whh: recurrence runs pure bf16)
__global__ void cvt4_kernel(const float* __restrict__ x, u16* __restrict__ y, int n4)
{
    const int stride = gridDim.x * blockDim.x;
    for (int i = blockIdx.x * blockDim.x + threadIdx.x; i < n4; i += stride) {
        const float4 v = ((const float4*)x)[i];
        uint2 hp;
        hp.x = (unsigned)f2bf(v.x) | ((unsigned)f2bf(v.y) << 16);
        hp.y = (unsigned)f2bf(v.z) | ((unsigned)f2bf(v.w) << 16);
        ((uint2*)y)[i] = hp;
    }
}

// ---------------------------------------------------------------------------
// bf16x3 MFMA GEMM (m97 structure): C[M,N] = A[M,K] @ W[N,K]^T + b1 + b2
// 128x128 tile, BK=32, 256 thr = 4 waves (2x2), global_load_lds staging,
// term-major MFMA. M,N%128==0, K%32==0, grid=1D bijective-XCD-swizzled.
// ---------------------------------------------------------------------------
template<bool EMIT>
__launch_bounds__(256)
__global__ void mfma_gemm(const u16* __restrict__ Ah, const u16* __restrict__ Al,
                          const u16* __restrict__ Wh, const u16* __restrict__ Wl,
                          const float* __restrict__ b1, const float* __restrict__ b2,
                          float* __restrict__ Cf, u16* __restrict__ Ch, u16* __restrict__ Cl,
                          int M, int N, int K, int nbx)
{
    __shared__ u16 sAh[4][128][8]; __shared__ u16 sAl[4][128][8];
    __shared__ u16 sWh[4][128][8]; __shared__ u16 sWl[4][128][8];
    const int tid = threadIdx.x, lane = tid & 63, w = tid >> 6;
    const int wr = w >> 1, wc = w & 1;

    const int nwg = gridDim.x;
    const int cpx = nwg >> 3;
    const int lg = (blockIdx.x & 7) * cpx + (blockIdx.x >> 3);
    const int m0 = (lg % nbx) * 128;
    const int n0 = (lg / nbx) * 128;

    const u16* Ah0 = Ah + (size_t)m0 * K;
    const u16* Al0 = Al + (size_t)m0 * K;
    const u16* Wh0 = Wh + (size_t)n0 * K;
    const u16* Wl0 = Wl + (size_t)n0 * K;

    f32x4 acc[4][4];
#pragma unroll
    for (int i = 0; i < 4; ++i)
#pragma unroll
        for (int j = 0; j < 4; ++j) acc[i][j] = f32x4{0.f, 0.f, 0.f, 0.f};

    const int u1 = tid, u2 = tid + 256;
    const size_t go1 = (size_t)(u1 & 127) * K + (u1 >> 7) * 8;
    const size_t go2 = (size_t)(u2 & 127) * K + (u2 >> 7) * 8;
    u16* const l1 = (u16*)sAh + (size_t)u1 * 8;
    u16* const l2 = (u16*)sAh + (size_t)u2 * 8;
    const size_t dAl = (u16*)sAl - (u16*)sAh;
    const size_t dWh = (u16*)sWh - (u16*)sAh;
    const size_t dWl = (u16*)sWl - (u16*)sAh;

    for (int k0 = 0; k0 < K; k0 += 32) {
        gld16(Ah0 + go1 + k0, l1);        gld16(Ah0 + go2 + k0, l2);
        gld16(Al0 + go1 + k0, l1 + dAl);  gld16(Al0 + go2 + k0, l2 + dAl);
        gld16(Wh0 + go1 + k0, l1 + dWh);  gld16(Wh0 + go2 + k0, l2 + dWh);
        gld16(Wl0 + go1 + k0, l1 + dWl);  gld16(Wl0 + go2 + k0, l2 + dWl);
        __syncthreads();

        const int kb = lane >> 4, rr = lane & 15;
        short8 Avh[4], Avl[4], Wvh[4], Wvl[4];
#pragma unroll
        for (int i = 0; i < 4; ++i) {
            Avh[i] = *(const short8*)&sAh[kb][wr * 64 + i * 16 + rr][0];
            Avl[i] = *(const short8*)&sAl[kb][wr * 64 + i * 16 + rr][0];
            Wvh[i] = *(const short8*)&sWh[kb][wc * 64 + i * 16 + rr][0];
            Wvl[i] = *(const short8*)&sWl[kb][wc * 64 + i * 16 + rr][0];
        }
#pragma unroll
        for (int i = 0; i < 4; ++i)
#pragma unroll
            for (int j = 0; j < 4; ++j)
                acc[i][j] = __builtin_amdgcn_mfma_f32_16x16x32_bf16(Avh[i], Wvh[j], acc[i][j], 0, 0, 0);
#pragma unroll
        for (int i = 0; i < 4; ++i)
#pragma unroll
            for (int j = 0; j < 4; ++j)
                acc[i][j] = __builtin_amdgcn_mfma_f32_16x16x32_bf16(Avh[i], Wvl[j], acc[i][j], 0, 0, 0);
#pragma unroll
        for (int i = 0; i < 4; ++i)
#pragma unroll
            for (int j = 0; j < 4; ++j)
                acc[i][j] = __builtin_amdgcn_mfma_f32_16x16x32_bf16(Avl[i], Wvh[j], acc[i][j], 0, 0, 0);
        __syncthreads();
    }

    const int rr = lane & 15, rg = lane >> 4;
#pragma unroll
    for (int j = 0; j < 4; ++j) {
        const int col = n0 + wc * 64 + j * 16 + rr;
        const float bias = (b1 ? b1[col] : 0.f) + (b2 ? b2[col] : 0.f);
#pragma unroll
        for (int i = 0; i < 4; ++i) {
#pragma unroll
            for (int q = 0; q < 4; ++q) {
                const int row = m0 + wr * 64 + i * 16 + rg * 4 + q;
                const float v = acc[i][j][q] + bias;
                if (EMIT) {
                    u16 h, l; split2(v, h, l);
                    Ch[(size_t)row * N + col] = h;
                    Cl[(size_t)row * N + col] = l;
                } else {
                    Cf[(size_t)row * N + col] = v;
                }
            }
        }
    }
}

// ---------------------------------------------------------------------------
// Pure-bf16 MFMA LSTM step: gates = h_in @ Whh^T + G, then cell update.
// Block: 512 threads = 8 waves (4x2), tile 128 batch x (32 j x 4 gates).
// Double-buffered 2-phase K-loop (T3 minimum): stage k+1 while computing k.
// W staged gate-interleaved via per-lane global source addresses so a lane
// owns all 4 gates of its (b, j) -> in-register cell update.
// ---------------------------------------------------------------------------
struct Step2 {
    const u16* Whh[2];     // plain bf16 [4096][1024]
    const float* G[2];     // [BT][4096], row = b*TT + t
    const u16* hin[2];     // [512][1024] bf16
    u16* hout[2];
    float* c[2]; float* hfin[2];
    int t[2];
};

__launch_bounds__(512)
__global__ void lstm_step_bf16(Step2 a, int do_gemm)
{
    const int l = blockIdx.z;
    __shared__ u16 sA[2][4][128][8];   // 2 x 8KB
    __shared__ u16 sW[2][4][128][8];
    const int tid = threadIdx.x, lane = tid & 63, w = tid >> 6;
    const int wr = w >> 1, wc = w & 1;     // 4 x 2 wave grid: 32 rows x 64 cols each
    const int m0 = blockIdx.x * 128;
    const int j0 = blockIdx.y * 32;

    const u16* __restrict__ hin = a.hin[l];
    const u16* __restrict__ Whh = a.Whh[l];

    f32x4 acc[2][4];   // [row-frag][gate]
#pragma unroll
    for (int i = 0; i < 2; ++i)
#pragma unroll
        for (int g = 0; g < 4; ++g) acc[i][g] = f32x4{0.f, 0.f, 0.f, 0.f};

    const int rr = lane & 15, rg = lane >> 4;

    if (do_gemm) {
        // staging addresses: thread u covers LDS row u&127, k-chunk (u>>7)*8
        const int r = tid & 127;
        const size_t goA = (size_t)(m0 + r) * HID + (tid >> 7) * 8;
        const int wrow = ((r >> 4) & 3) * HID + j0 + (r >> 6) * 16 + (r & 15);
        const size_t goW = (size_t)wrow * HID + (tid >> 7) * 8;
        u16* const ldA = (u16*)sA + (size_t)tid * 8;
        u16* const ldW = (u16*)sW + (size_t)tid * 8;

        // prologue: stage k0=0 into buffer 0
        gld16(hin + goA, ldA);
        gld16(Whh + goW, ldW);
        __syncthreads();

        for (int k0 = 0; k0 < HID; k0 += 32) {
            const int bf = (k0 >> 5) & 1;
            if (k0 + 32 < HID) {             // stage next tile into other buffer
                gld16(hin + goA + k0 + 32, ldA + (bf ^ 1) * 4096);
                gld16(Whh + goW + k0 + 32, ldW + (bf ^ 1) * 4096);
            }
            const int kb = lane >> 4;
            short8 Av[2], Wv[4];
#pragma unroll
            for (int i = 0; i < 2; ++i)
                Av[i] = *(const short8*)&sA[bf][kb][wr * 32 + i * 16 + rr][0];
#pragma unroll
            for (int g = 0; g < 4; ++g)
                Wv[g] = *(const short8*)&sW[bf][kb][wc * 64 + g * 16 + rr][0];
#pragma unroll
            for (int i = 0; i < 2; ++i)
#pragma unroll
                for (int g = 0; g < 4; ++g)
                    acc[i][g] = __builtin_amdgcn_mfma_f32_16x16x32_bf16(Av[i], Wv[g], acc[i][g], 0, 0, 0);
            __syncthreads();   // drains vmcnt (staged loads) + lgkm before reuse
        }
    }

    const int j = j0 + wc * 16 + rr;
    const int t = a.t[l];
    const float* __restrict__ G = a.G[l];
    float* __restrict__ cb = a.c[l];
    float* __restrict__ hf = a.hfin[l];
    u16* __restrict__ ho = a.hout[l];
#pragma unroll
    for (int i = 0; i < 2; ++i) {
#pragma unroll
        for (int q = 0; q < 4; ++q) {
            const int b = m0 + wr * 32 + i * 16 + rg * 4 + q;
            const float* gp = G + ((size_t)b * TT + t) * G4 + j;
            const float pi = acc[i][0][q] + gp[0];
            const float pf = acc[i][1][q] + gp[1024];
            const float pg = acc[i][2][q] + gp[2048];
            const float po = acc[i][3][q] + gp[3072];
            const size_t idx = (size_t)b * HID + j;
            const float cn = sigf(pf) * cb[idx] + sigf(pi) * tanhf(pg);
            cb[idx] = cn;
            const float h = sigf(po) * tanhf(cn);
            hf[idx] = h;
            ho[idx] = f2bf(h);
        }
    }
}

// fused[b, n] = prod over streams of concat(h_fwd, h_rev); hfin layout [l][b][j]
__global__ void fuse_mul_kernel(const float* __restrict__ hfin, float* __restrict__ fused)
{
    const int idx = blockIdx.x * blockDim.x + threadIdx.x;
    if (idx >= BATCH * 2 * HID) return;
    const int b = idx >> 11;
    const int n = idx & 2047;
    const int half = n >> 10;
    const int j = n & 1023;
    const size_t o = (size_t)b * HID + j;
    const size_t S = (size_t)BATCH * HID;
    fused[idx] = hfin[(size_t)(0 + half) * S + o] *
                 hfin[(size_t)(2 + half) * S + o] *
                 hfin[(size_t)(4 + half) * S + o];
}

// fp32 vector GEMM for the small classifier (N=200): C = A@W^T + b
__launch_bounds__(256)
__global__ void gemm_bias_kernel(const float* __restrict__ A, const float* __restrict__ W,
                                 const float* __restrict__ b1,
                                 float* __restrict__ C, int M, int N, int K)
{
    __shared__ float As[16][68];
    __shared__ float Ws[16][68];
    const int tid = threadIdx.x;
    const int tx = tid & 15, ty = tid >> 4;
    const int m0 = blockIdx.x * 64;
    const int n0 = blockIdx.y * 64;
    const int lr = tid >> 2;
    const int lk = (tid & 3) << 2;
    const bool mok = (m0 + lr < M);
    const bool nok = (n0 + lr < N);
    const float* Arow = A + (size_t)(m0 + lr) * K + lk;
    const float* Wrow = W + (size_t)(n0 + lr) * K + lk;
    float acc[4][4] = {};

    for (int k0 = 0; k0 < K; k0 += 16) {
        float4 av = make_float4(0.f, 0.f, 0.f, 0.f);
        float4 wv = make_float4(0.f, 0.f, 0.f, 0.f);
        if (mok) av = *(const float4*)(Arow + k0);
        if (nok) wv = *(const float4*)(Wrow + k0);
        As[lk + 0][lr] = av.x; As[lk + 1][lr] = av.y; As[lk + 2][lr] = av.z; As[lk + 3][lr] = av.w;
        Ws[lk + 0][lr] = wv.x; Ws[lk + 1][lr] = wv.y; Ws[lk + 2][lr] = wv.z; Ws[lk + 3][lr] = wv.w;
        __syncthreads();
#pragma unroll
        for (int k = 0; k < 16; ++k) {
            const float4 a = *(const float4*)&As[k][ty << 2];
            const float4 ww = *(const float4*)&Ws[k][tx << 2];
            const float a4[4] = {a.x, a.y, a.z, a.w};
            const float w4[4] = {ww.x, ww.y, ww.z, ww.w};
#pragma unroll
            for (int i = 0; i < 4; ++i)
#pragma unroll
                for (int j = 0; j < 4; ++j)
                    acc[i][j] = fmaf(a4[i], w4[j], acc[i][j]);
        }
        __syncthreads();
    }

#pragma unroll
    for (int i = 0; i < 4; ++i) {
        const int m = m0 + (ty << 2) + i;
        if (m >= M) continue;
#pragma unroll
        for (int j = 0; j < 4; ++j) {
            const int n = n0 + (tx << 2) + j;
            if (n >= N) continue;
            C[(size_t)m * N + n] = acc[i][j] + (b1 ? b1[n] : 0.f);
        }
    }
}

extern "C" void kernel_launch(void* const* d_in, const int* in_sizes, int n_in,
                              void* d_out, int out_size, void* d_ws, size_t ws_size,
                              hipStream_t stream)
{
    const float* resnet   = (const float*)d_in[0];
    const float* c3d      = (const float*)d_in[1];
    const float* audio    = (const float*)d_in[2];
    const float* W_audio  = (const float*)d_in[3];
    const float* b_audio  = (const float*)d_in[4];
    const float* W_resnet = (const float*)d_in[5];
    const float* b_resnet = (const float*)d_in[6];
    const float* W_c3d    = (const float*)d_in[7];
    const float* b_c3d    = (const float*)d_in[8];
    const float* Wih[6]; const float* Whh[6]; const float* bih[6]; const float* bhh[6];
    for (int l = 0; l < 6; ++l) {
        Wih[l] = (const float*)d_in[9 + 4 * l];
        Whh[l] = (const float*)d_in[10 + 4 * l];
        bih[l] = (const float*)d_in[11 + 4 * l];
        bhh[l] = (const float*)d_in[12 + 4 * l];
    }
    const float* W_out = (const float*)d_in[33];
    const float* b_out = (const float*)d_in[34];
    float* out = (float*)d_out;

    const float* feat[3] = { audio, resnet, c3d };
    const float* fb[3]   = { b_audio, b_resnet, b_c3d };
    const int    fK[3]   = { 128, 2048, 4096 };

    // ---- workspace carve (bytes); feat/proj/Wih/Whh buffers reused per stream ----
    char* p = (char*)d_ws;
    char* pend = p + ws_size;
    auto alloc = [&](size_t bytes) -> void* {
        void* q = p; p += (bytes + 255) & ~(size_t)255; return q;
    };
    const size_t FW = (size_t)1024 * (128 + 2048 + 4096);
    u16* featH = (u16*)alloc((size_t)BT * 4096 * 2);
    u16* featL = (u16*)alloc((size_t)BT * 4096 * 2);
    u16* fwH   = (u16*)alloc(FW * 2);
    u16* fwL   = (u16*)alloc(FW * 2);
    u16* wihH  = (u16*)alloc((size_t)2 * G4 * HID * 2);
    u16* wihL  = (u16*)alloc((size_t)2 * G4 * HID * 2);
    u16* whhB  = (u16*)alloc((size_t)2 * G4 * HID * 2);     // plain bf16
    u16* projH = (u16*)alloc((size_t)BT * HID * 2);
    u16* projL = (u16*)alloc((size_t)BT * HID * 2);
    float* G   = (float*)alloc((size_t)2 * BT * G4 * 4);
    u16* hA    = (u16*)alloc((size_t)2 * BATCH * HID * 2);  // bf16 ping-pong
    u16* hB    = (u16*)alloc((size_t)2 * BATCH * HID * 2);
    float* cb    = (float*)alloc((size_t)2 * BATCH * HID * 4);
    float* hfin  = (float*)alloc((size_t)6 * BATCH * HID * 4);
    float* fused = (float*)alloc((size_t)BATCH * 2 * HID * 4);
    if (p > pend) {
        fprintf(stderr, "kernel_launch: ws too small: need %zu have %zu\n",
                (size_t)(p - (char*)d_ws), ws_size);
        return;
    }

    const dim3 blk(256);
    const size_t fwOff[3] = { 0, (size_t)1024 * 128, (size_t)1024 * 128 + (size_t)1024 * 2048 };
    const size_t S = (size_t)BATCH * HID;

    // split the three projection weight matrices (once)
    for (int st = 0; st < 3; ++st) {
        const int n4 = (1024 * fK[st]) / 4;
        split4_kernel<<<dim3(min(2048, (n4 + 255) / 256)), blk, 0, stream>>>(
            (st == 0 ? W_audio : st == 1 ? W_resnet : W_c3d), fwH + fwOff[st], fwL + fwOff[st], n4);
    }

    for (int st = 0; st < 3; ++st) {
        const int K = fK[st];
        // split features
        split4_kernel<<<dim3(2048), blk, 0, stream>>>(feat[st], featH, featL, (BT * K) / 4);
        // projection -> split proj (bf16x3)
        mfma_gemm<true><<<dim3((BT / 128) * (HID / 128)), blk, 0, stream>>>(
            featH, featL, fwH + fwOff[st], fwL + fwOff[st], fb[st], nullptr,
            nullptr, projH, projL, BT, HID, K, BT / 128);
        // per direction: split Wih (for bf16x3 G GEMM), cvt Whh to plain bf16, G GEMM
        for (int d = 0; d < 2; ++d) {
            const int l = st * 2 + d;
            const size_t woff = (size_t)d * G4 * HID;
            split4_kernel<<<dim3(2048), blk, 0, stream>>>(Wih[l], wihH + woff, wihL + woff, (G4 * HID) / 4);
            cvt4_kernel<<<dim3(2048), blk, 0, stream>>>(Whh[l], whhB + woff, (G4 * HID) / 4);
            mfma_gemm<false><<<dim3((BT / 128) * (G4 / 128)), blk, 0, stream>>>(
                projH, projL, wihH + woff, wihL + woff, bih[l], bhh[l],
                G + (size_t)d * BT * G4, nullptr, nullptr, BT, G4, HID, BT / 128);
        }

        hipMemsetAsync(cb, 0, (size_t)2 * BATCH * HID * 4, stream);

        for (int s = 0; s < TT; ++s) {
            Step2 a;
            u16* in  = (s & 1) ? hB : hA;
            u16* o   = (s & 1) ? hA : hB;
            for (int d = 0; d < 2; ++d) {
                const int l = st * 2 + d;
                const size_t woff = (size_t)d * G4 * HID;
                const size_t hoff = (size_t)d * BATCH * HID;
                a.Whh[d]  = whhB + woff;
                a.G[d]    = G + (size_t)d * BT * G4;
                a.hin[d]  = in + hoff;
                a.hout[d] = o + hoff;
                a.c[d]    = cb + hoff;
                a.hfin[d] = hfin + (size_t)l * S;
                a.t[d]    = d ? (TT - 1 - s) : s;
            }
            lstm_step_bf16<<<dim3(BATCH / 128, HID / 32, 2), dim3(512), 0, stream>>>(a, s > 0 ? 1 : 0);
        }
    }

    // fused elementwise product
    fuse_mul_kernel<<<dim3((BATCH * 2 * HID) / 256), blk, 0, stream>>>(hfin, fused);

    // classifier
    gemm_bias_kernel<<<dim3(BATCH / 64, (NCLS + 63) / 64), blk, 0, stream>>>(
        fused, W_out, b_out, out, BATCH, NCLS, 2 * HID);
}

// Round 7
// 5343.922 us; speedup vs baseline: 1.4567x; 1.0085x over previous
//
#include <hip/hip_runtime.h>
#include <cstdio>
#include <cstdint>

#define TT    20
#define BATCH 512
#define HID   1024
#define G4    4096
#define NG    8192          // both directions' gates, merged
#define BT    (BATCH * TT)  // 10240
#define NCLS  200

typedef unsigned short u16;
typedef __attribute__((ext_vector_type(8))) short short8;   // 8 bf16 (4 VGPRs)
typedef __attribute__((ext_vector_type(4))) float f32x4;

__device__ __forceinline__ float sigf(float x) { return 1.0f / (1.0f + __expf(-x)); }

__device__ __forceinline__ u16 f2bf(float x) {
    unsigned u = __float_as_uint(x);
    u += 0x7FFFu + ((u >> 16) & 1u);           // RNE
    return (u16)(u >> 16);
}
__device__ __forceinline__ float bf2f(u16 b) { return __uint_as_float(((unsigned)b) << 16); }
__device__ __forceinline__ void split2(float x, u16& h, u16& l) {
    h = f2bf(x);
    l = f2bf(x - bf2f(h));
}

// async 16B global -> LDS; LDS dest must be linear in lane order
__device__ __forceinline__ void gld16(const u16* g, u16* l) {
    __builtin_amdgcn_global_load_lds(
        (const __attribute__((address_space(1))) void*)g,
        (__attribute__((address_space(3))) void*)l, 16, 0, 0);
}

// vectorized fp32 -> (hi, lo) bf16 split, float4 per thread
__global__ void split4_kernel(const float* __restrict__ x, u16* __restrict__ hi,
                              u16* __restrict__ lo, int n4)
{
    const int stride = gridDim.x * blockDim.x;
    for (int i = blockIdx.x * blockDim.x + threadIdx.x; i < n4; i += stride) {
        const float4 v = ((const float4*)x)[i];
        u16 h0,l0,h1,l1,h2,l2,h3,l3;
        split2(v.x,h0,l0); split2(v.y,h1,l1); split2(v.z,h2,l2); split2(v.w,h3,l3);
        uint2 hp, lp;
        hp.x = (unsigned)h0 | ((unsigned)h1 << 16); hp.y = (unsigned)h2 | ((unsigned)h3 << 16);
        lp.x = (unsigned)l0 | ((unsigned)l1 << 16); lp.y = (unsigned)l2 | ((unsigned)l3 << 16);
        ((uint2*)hi)[i] = hp; ((uint2*)lo)[i] = lp;
    }
}

// vectorized fp32 -> plain bf16 convert (for Whh: recurrence runs pure bf16)
__global__ void cvt4_kernel(const float* __restrict__ x, u16* __restrict__ y, int n4)
{
    const int stride = gridDim.x * blockDim.x;
    for (int i = blockIdx.x * blockDim.x + threadIdx.x; i < n4; i += stride) {
        const float4 v = ((const float4*)x)[i];
        uint2 hp;
        hp.x = (unsigned)f2bf(v.x) | ((unsigned)f2bf(v.y) << 16);
        hp.y = (unsigned)f2bf(v.z) | ((unsigned)f2bf(v.w) << 16);
        ((uint2*)y)[i] = hp;
    }
}

// bcat[0:4096] = bih0+bhh0 ; bcat[4096:8192] = bih1+bhh1
__global__ void bias_cat_kernel(const float* __restrict__ bi0, const float* __restrict__ bh0,
                                const float* __restrict__ bi1, const float* __restrict__ bh1,
                                float* __restrict__ bcat)
{
    const int n = blockIdx.x * blockDim.x + threadIdx.x;
    if (n >= NG) return;
    bcat[n] = (n < G4) ? (bi0[n] + bh0[n]) : (bi1[n - G4] + bh1[n - G4]);
}

// ---------------------------------------------------------------------------
// bf16x3 MFMA GEMM (m97 structure): C[M,N] = A[M,K] @ W[N,K]^T + b1 + b2
// 128x128 tile, BK=32, 256 thr = 4 waves (2x2), global_load_lds staging,
// term-major MFMA. M,N%128==0, K%32==0.
// 1D grid, bijective XCD swizzle, then CHUNKED supertile mapping:
// chunks of (cm m-tiles x all n-tiles), m-fastest within a chunk, so the
// concurrent working set (A-strip + W-window) stays L3-resident.
// Requires (M/128) % cm == 0 and nwg % 8 == 0.
// ---------------------------------------------------------------------------
template<bool EMIT>
__launch_bounds__(256)
__global__ void mfma_gemm(const u16* __restrict__ Ah, const u16* __restrict__ Al,
                          const u16* __restrict__ Wh, const u16* __restrict__ Wl,
                          const float* __restrict__ b1, const float* __restrict__ b2,
                          float* __restrict__ Cf, u16* __restrict__ Ch, u16* __restrict__ Cl,
                          int M, int N, int K, int cm)
{
    __shared__ u16 sAh[4][128][8]; __shared__ u16 sAl[4][128][8];
    __shared__ u16 sWh[4][128][8]; __shared__ u16 sWl[4][128][8];
    const int tid = threadIdx.x, lane = tid & 63, w = tid >> 6;
    const int wr = w >> 1, wc = w & 1;

    // XCD swizzle (bijective: nwg % 8 == 0)
    const int nwg = gridDim.x;
    const int cpx = nwg >> 3;
    const int lg = (blockIdx.x & 7) * cpx + (blockIdx.x >> 3);
    // chunked supertile mapping
    const int nby = N >> 7;
    const int cb = cm * nby;           // blocks per chunk
    const int chunk = lg / cb;
    const int r = lg - chunk * cb;
    const int m0 = (chunk * cm + (r % cm)) * 128;
    const int n0 = (r / cm) * 128;

    const u16* Ah0 = Ah + (size_t)m0 * K;
    const u16* Al0 = Al + (size_t)m0 * K;
    const u16* Wh0 = Wh + (size_t)n0 * K;
    const u16* Wl0 = Wl + (size_t)n0 * K;

    f32x4 acc[4][4];
#pragma unroll
    for (int i = 0; i < 4; ++i)
#pragma unroll
        for (int j = 0; j < 4; ++j) acc[i][j] = f32x4{0.f, 0.f, 0.f, 0.f};

    const int u1 = tid, u2 = tid + 256;
    const size_t go1 = (size_t)(u1 & 127) * K + (u1 >> 7) * 8;
    const size_t go2 = (size_t)(u2 & 127) * K + (u2 >> 7) * 8;
    u16* const l1 = (u16*)sAh + (size_t)u1 * 8;
    u16* const l2 = (u16*)sAh + (size_t)u2 * 8;
    const size_t dAl = (u16*)sAl - (u16*)sAh;
    const size_t dWh = (u16*)sWh - (u16*)sAh;
    const size_t dWl = (u16*)sWl - (u16*)sAh;

    for (int k0 = 0; k0 < K; k0 += 32) {
        gld16(Ah0 + go1 + k0, l1);        gld16(Ah0 + go2 + k0, l2);
        gld16(Al0 + go1 + k0, l1 + dAl);  gld16(Al0 + go2 + k0, l2 + dAl);
        gld16(Wh0 + go1 + k0, l1 + dWh);  gld16(Wh0 + go2 + k0, l2 + dWh);
        gld16(Wl0 + go1 + k0, l1 + dWl);  gld16(Wl0 + go2 + k0, l2 + dWl);
        __syncthreads();

        const int kb = lane >> 4, rr = lane & 15;
        short8 Avh[4], Avl[4], Wvh[4], Wvl[4];
#pragma unroll
        for (int i = 0; i < 4; ++i) {
            Avh[i] = *(const short8*)&sAh[kb][wr * 64 + i * 16 + rr][0];
            Avl[i] = *(const short8*)&sAl[kb][wr * 64 + i * 16 + rr][0];
            Wvh[i] = *(const short8*)&sWh[kb][wc * 64 + i * 16 + rr][0];
            Wvl[i] = *(const short8*)&sWl[kb][wc * 64 + i * 16 + rr][0];
        }
#pragma unroll
        for (int i = 0; i < 4; ++i)
#pragma unroll
            for (int j = 0; j < 4; ++j)
                acc[i][j] = __builtin_amdgcn_mfma_f32_16x16x32_bf16(Avh[i], Wvh[j], acc[i][j], 0, 0, 0);
#pragma unroll
        for (int i = 0; i < 4; ++i)
#pragma unroll
            for (int j = 0; j < 4; ++j)
                acc[i][j] = __builtin_amdgcn_mfma_f32_16x16x32_bf16(Avh[i], Wvl[j], acc[i][j], 0, 0, 0);
#pragma unroll
        for (int i = 0; i < 4; ++i)
#pragma unroll
            for (int j = 0; j < 4; ++j)
                acc[i][j] = __builtin_amdgcn_mfma_f32_16x16x32_bf16(Avl[i], Wvh[j], acc[i][j], 0, 0, 0);
        __syncthreads();
    }

    const int rr = lane & 15, rg = lane >> 4;
#pragma unroll
    for (int j = 0; j < 4; ++j) {
        const int col = n0 + wc * 64 + j * 16 + rr;
        const float bias = (b1 ? b1[col] : 0.f) + (b2 ? b2[col] : 0.f);
#pragma unroll
        for (int i = 0; i < 4; ++i) {
#pragma unroll
            for (int q = 0; q < 4; ++q) {
                const int row = m0 + wr * 64 + i * 16 + rg * 4 + q;
                const float v = acc[i][j][q] + bias;
                if (EMIT) {
                    u16 h, l; split2(v, h, l);
                    Ch[(size_t)row * N + col] = h;
                    Cl[(size_t)row * N + col] = l;
                } else {
                    Cf[(size_t)row * N + col] = v;
                }
            }
        }
    }
}

// ---------------------------------------------------------------------------
// Pure-bf16 MFMA LSTM step: gates = h_in @ Whh^T + G, then cell update.
// Block: 512 threads = 8 waves (4x2), tile 128 batch x (32 j x 4 gates).
// Double-buffered 2-phase K-loop. G rows have stride NG (merged layout);
// column for (d, gate, j) = d*4096 + gate*1024 + j.
// ---------------------------------------------------------------------------
struct Step2 {
    const u16* Whh[2];     // plain bf16 [4096][1024]
    const float* G[2];     // base + d*G4, row stride NG, row = b*TT + t
    const u16* hin[2];     // [512][1024] bf16
    u16* hout[2];
    float* c[2]; float* hfin[2];
    int t[2];
};

__launch_bounds__(512)
__global__ void lstm_step_bf16(Step2 a, int do_gemm)
{
    const int l = blockIdx.z;
    __shared__ u16 sA[2][4][128][8];   // 2 x 8KB
    __shared__ u16 sW[2][4][128][8];
    const int tid = threadIdx.x, lane = tid & 63, w = tid >> 6;
    const int wr = w >> 1, wc = w & 1;     // 4 x 2 wave grid: 32 rows x 64 cols each
    const int m0 = blockIdx.x * 128;
    const int j0 = blockIdx.y * 32;

    const u16* __restrict__ hin = a.hin[l];
    const u16* __restrict__ Whh = a.Whh[l];

    f32x4 acc[2][4];   // [row-frag][gate]
#pragma unroll
    for (int i = 0; i < 2; ++i)
#pragma unroll
        for (int g = 0; g < 4; ++g) acc[i][g] = f32x4{0.f, 0.f, 0.f, 0.f};

    const int rr = lane & 15, rg = lane >> 4;

    if (do_gemm) {
        const int r = tid & 127;
        const size_t goA = (size_t)(m0 + r) * HID + (tid >> 7) * 8;
        const int wrow = ((r >> 4) & 3) * HID + j0 + (r >> 6) * 16 + (r & 15);
        const size_t goW = (size_t)wrow * HID + (tid >> 7) * 8;
        u16* const ldA = (u16*)sA + (size_t)tid * 8;
        u16* const ldW = (u16*)sW + (size_t)tid * 8;

        gld16(hin + goA, ldA);
        gld16(Whh + goW, ldW);
        __syncthreads();

        for (int k0 = 0; k0 < HID; k0 += 32) {
            const int bf = (k0 >> 5) & 1;
            if (k0 + 32 < HID) {
                gld16(hin + goA + k0 + 32, ldA + (bf ^ 1) * 4096);
                gld16(Whh + goW + k0 + 32, ldW + (bf ^ 1) * 4096);
            }
            const int kb = lane >> 4;
            short8 Av[2], Wv[4];
#pragma unroll
            for (int i = 0; i < 2; ++i)
                Av[i] = *(const short8*)&sA[bf][kb][wr * 32 + i * 16 + rr][0];
#pragma unroll
            for (int g = 0; g < 4; ++g)
                Wv[g] = *(const short8*)&sW[bf][kb][wc * 64 + g * 16 + rr][0];
#pragma unroll
            for (int i = 0; i < 2; ++i)
#pragma unroll
                for (int g = 0; g < 4; ++g)
                    acc[i][g] = __builtin_amdgcn_mfma_f32_16x16x32_bf16(Av[i], Wv[g], acc[i][g], 0, 0, 0);
            __syncthreads();
        }
    }

    const int j = j0 + wc * 16 + rr;
    const int t = a.t[l];
    const float* __restrict__ G = a.G[l];
    float* __restrict__ cb = a.c[l];
    float* __restrict__ hf = a.hfin[l];
    u16* __restrict__ ho = a.hout[l];
#pragma unroll
    for (int i = 0; i < 2; ++i) {
#pragma unroll
        for (int q = 0; q < 4; ++q) {
            const int b = m0 + wr * 32 + i * 16 + rg * 4 + q;
            const float* gp = G + ((size_t)b * TT + t) * NG + j;
            const float pi = acc[i][0][q] + gp[0];
            const float pf = acc[i][1][q] + gp[1024];
            const float pg = acc[i][2][q] + gp[2048];
            const float po = acc[i][3][q] + gp[3072];
            const size_t idx = (size_t)b * HID + j;
            const float cn = sigf(pf) * cb[idx] + sigf(pi) * tanhf(pg);
            cb[idx] = cn;
            const float h = sigf(po) * tanhf(cn);
            hf[idx] = h;
            ho[idx] = f2bf(h);
        }
    }
}

// fused[b, n] = prod over streams of concat(h_fwd, h_rev); hfin layout [l][b][j]
__global__ void fuse_mul_kernel(const float* __restrict__ hfin, float* __restrict__ fused)
{
    const int idx = blockIdx.x * blockDim.x + threadIdx.x;
    if (idx >= BATCH * 2 * HID) return;
    const int b = idx >> 11;
    const int n = idx & 2047;
    const int half = n >> 10;
    const int j = n & 1023;
    const size_t o = (size_t)b * HID + j;
    const size_t S = (size_t)BATCH * HID;
    fused[idx] = hfin[(size_t)(0 + half) * S + o] *
                 hfin[(size_t)(2 + half) * S + o] *
                 hfin[(size_t)(4 + half) * S + o];
}

// fp32 vector GEMM for the small classifier (N=200): C = A@W^T + b
__launch_bounds__(256)
__global__ void gemm_bias_kernel(const float* __restrict__ A, const float* __restrict__ W,
                                 const float* __restrict__ b1,
                                 float* __restrict__ C, int M, int N, int K)
{
    __shared__ float As[16][68];
    __shared__ float Ws[16][68];
    const int tid = threadIdx.x;
    const int tx = tid & 15, ty = tid >> 4;
    const int m0 = blockIdx.x * 64;
    const int n0 = blockIdx.y * 64;
    const int lr = tid >> 2;
    const int lk = (tid & 3) << 2;
    const bool mok = (m0 + lr < M);
    const bool nok = (n0 + lr < N);
    const float* Arow = A + (size_t)(m0 + lr) * K + lk;
    const float* Wrow = W + (size_t)(n0 + lr) * K + lk;
    float acc[4][4] = {};

    for (int k0 = 0; k0 < K; k0 += 16) {
        float4 av = make_float4(0.f, 0.f, 0.f, 0.f);
        float4 wv = make_float4(0.f, 0.f, 0.f, 0.f);
        if (mok) av = *(const float4*)(Arow + k0);
        if (nok) wv = *(const float4*)(Wrow + k0);
        As[lk + 0][lr] = av.x; As[lk + 1][lr] = av.y; As[lk + 2][lr] = av.z; As[lk + 3][lr] = av.w;
        Ws[lk + 0][lr] = wv.x; Ws[lk + 1][lr] = wv.y; Ws[lk + 2][lr] = wv.z; Ws[lk + 3][lr] = wv.w;
        __syncthreads();
#pragma unroll
        for (int k = 0; k < 16; ++k) {
            const float4 a = *(const float4*)&As[k][ty << 2];
            const float4 ww = *(const float4*)&Ws[k][tx << 2];
            const float a4[4] = {a.x, a.y, a.z, a.w};
            const float w4[4] = {ww.x, ww.y, ww.z, ww.w};
#pragma unroll
            for (int i = 0; i < 4; ++i)
#pragma unroll
                for (int j = 0; j < 4; ++j)
                    acc[i][j] = fmaf(a4[i], w4[j], acc[i][j]);
        }
        __syncthreads();
    }

#pragma unroll
    for (int i = 0; i < 4; ++i) {
        const int m = m0 + (ty << 2) + i;
        if (m >= M) continue;
#pragma unroll
        for (int j = 0; j < 4; ++j) {
            const int n = n0 + (tx << 2) + j;
            if (n >= N) continue;
            C[(size_t)m * N + n] = acc[i][j] + (b1 ? b1[n] : 0.f);
        }
    }
}

extern "C" void kernel_launch(void* const* d_in, const int* in_sizes, int n_in,
                              void* d_out, int out_size, void* d_ws, size_t ws_size,
                              hipStream_t stream)
{
    const float* resnet   = (const float*)d_in[0];
    const float* c3d      = (const float*)d_in[1];
    const float* audio    = (const float*)d_in[2];
    const float* W_audio  = (const float*)d_in[3];
    const float* b_audio  = (const float*)d_in[4];
    const float* W_resnet = (const float*)d_in[5];
    const float* b_resnet = (const float*)d_in[6];
    const float* W_c3d    = (const float*)d_in[7];
    const float* b_c3d    = (const float*)d_in[8];
    const float* Wih[6]; const float* Whh[6]; const float* bih[6]; const float* bhh[6];
    for (int l = 0; l < 6; ++l) {
        Wih[l] = (const float*)d_in[9 + 4 * l];
        Whh[l] = (const float*)d_in[10 + 4 * l];
        bih[l] = (const float*)d_in[11 + 4 * l];
        bhh[l] = (const float*)d_in[12 + 4 * l];
    }
    const float* W_out = (const float*)d_in[33];
    const float* b_out = (const float*)d_in[34];
    float* out = (float*)d_out;

    const float* feat[3] = { audio, resnet, c3d };
    const float* fb[3]   = { b_audio, b_resnet, b_c3d };
    const int    fK[3]   = { 128, 2048, 4096 };

    // ---- workspace carve (bytes); feat/proj/Wih/Whh buffers reused per stream ----
    char* p = (char*)d_ws;
    char* pend = p + ws_size;
    auto alloc = [&](size_t bytes) -> void* {
        void* q = p; p += (bytes + 255) & ~(size_t)255; return q;
    };
    const size_t FW = (size_t)1024 * (128 + 2048 + 4096);
    u16* featH = (u16*)alloc((size_t)BT * 4096 * 2);
    u16* featL = (u16*)alloc((size_t)BT * 4096 * 2);
    u16* fwH   = (u16*)alloc(FW * 2);
    u16* fwL   = (u16*)alloc(FW * 2);
    u16* wihH  = (u16*)alloc((size_t)NG * HID * 2);          // both dirs, d-major
    u16* wihL  = (u16*)alloc((size_t)NG * HID * 2);
    u16* whhB  = (u16*)alloc((size_t)NG * HID * 2);          // plain bf16, d-major
    u16* projH = (u16*)alloc((size_t)BT * HID * 2);
    u16* projL = (u16*)alloc((size_t)BT * HID * 2);
    float* G   = (float*)alloc((size_t)BT * NG * 4);         // merged [BT][8192]
    float* bcat = (float*)alloc((size_t)NG * 4);
    u16* hA    = (u16*)alloc((size_t)2 * BATCH * HID * 2);   // bf16 ping-pong
    u16* hB    = (u16*)alloc((size_t)2 * BATCH * HID * 2);
    float* cb    = (float*)alloc((size_t)2 * BATCH * HID * 4);
    float* hfin  = (float*)alloc((size_t)6 * BATCH * HID * 4);
    float* fused = (float*)alloc((size_t)BATCH * 2 * HID * 4);
    if (p > pend) {
        fprintf(stderr, "kernel_launch: ws too small: need %zu have %zu\n",
                (size_t)(p - (char*)d_ws), ws_size);
        return;
    }

    const dim3 blk(256);
    const size_t fwOff[3] = { 0, (size_t)1024 * 128, (size_t)1024 * 128 + (size_t)1024 * 2048 };
    const size_t S = (size_t)BATCH * HID;

    // split the three projection weight matrices (once)
    for (int st = 0; st < 3; ++st) {
        const int n4 = (1024 * fK[st]) / 4;
        split4_kernel<<<dim3(min(2048, (n4 + 255) / 256)), blk, 0, stream>>>(
            (st == 0 ? W_audio : st == 1 ? W_resnet : W_c3d), fwH + fwOff[st], fwL + fwOff[st], n4);
    }

    for (int st = 0; st < 3; ++st) {
        const int K = fK[st];
        // split features
        split4_kernel<<<dim3(2048), blk, 0, stream>>>(feat[st], featH, featL, (BT * K) / 4);
        // projection -> split proj (bf16x3); chunked mapping cm=16
        mfma_gemm<true><<<dim3((BT / 128) * (HID / 128)), blk, 0, stream>>>(
            featH, featL, fwH + fwOff[st], fwL + fwOff[st], fb[st], nullptr,
            nullptr, projH, projL, BT, HID, K, 16);
        // split Wih / cvt Whh (both directions, d-major contiguous)
        for (int d = 0; d < 2; ++d) {
            const int l = st * 2 + d;
            const size_t woff = (size_t)d * G4 * HID;
            split4_kernel<<<dim3(2048), blk, 0, stream>>>(Wih[l], wihH + woff, wihL + woff, (G4 * HID) / 4);
            cvt4_kernel<<<dim3(2048), blk, 0, stream>>>(Whh[l], whhB + woff, (G4 * HID) / 4);
        }
        // combined bias, merged G GEMM: G = proj @ [Wih_f; Wih_r]^T + bcat  (N=8192)
        bias_cat_kernel<<<dim3(NG / 256), blk, 0, stream>>>(
            bih[st * 2], bhh[st * 2], bih[st * 2 + 1], bhh[st * 2 + 1], bcat);
        mfma_gemm<false><<<dim3((BT / 128) * (NG / 128)), blk, 0, stream>>>(
            projH, projL, wihH, wihL, bcat, nullptr,
            G, nullptr, nullptr, BT, NG, HID, 40);

        hipMemsetAsync(cb, 0, (size_t)2 * BATCH * HID * 4, stream);

        for (int s = 0; s < TT; ++s) {
            Step2 a;
            u16* in  = (s & 1) ? hB : hA;
            u16* o   = (s & 1) ? hA : hB;
            for (int d = 0; d < 2; ++d) {
                const int l = st * 2 + d;
                const size_t woff = (size_t)d * G4 * HID;
                const size_t hoff = (size_t)d * BATCH * HID;
                a.Whh[d]  = whhB + woff;
                a.G[d]    = G + (size_t)d * G4;     // column offset in merged layout
                a.hin[d]  = in + hoff;
                a.hout[d] = o + hoff;
                a.c[d]    = cb + hoff;
                a.hfin[d] = hfin + (size_t)l * S;
                a.t[d]    = d ? (TT - 1 - s) : s;
            }
            lstm_step_bf16<<<dim3(BATCH / 128, HID / 32, 2), dim3(512), 0, stream>>>(a, s > 0 ? 1 : 0);
        }
    }

    // fused elementwise product
    fuse_mul_kernel<<<dim3((BATCH * 2 * HID) / 256), blk, 0, stream>>>(hfin, fused);

    // classifier
    gemm_bias_kernel<<<dim3(BATCH / 64, (NCLS + 63) / 64), blk, 0, stream>>>(
        fused, W_out, b_out, out, BATCH, NCLS, 2 * HID);
}

// Round 8
// 5250.595 us; speedup vs baseline: 1.4826x; 1.0178x over previous
//
#include <hip/hip_runtime.h>
#include <cstdio>
#include <cstdint>

#define TT    20
#define BATCH 512
#define HID   1024
#define G4    4096
#define NG    8192          // both directions' gates, merged
#define BT    (BATCH * TT)  // 10240
#define NCLS  200

typedef unsigned short u16;
typedef __attribute__((ext_vector_type(8))) short short8;   // 8 bf16 (4 VGPRs)
typedef __attribute__((ext_vector_type(4))) float f32x4;

__device__ __forceinline__ float sigf(float x) { return 1.0f / (1.0f + __expf(-x)); }

__device__ __forceinline__ u16 f2bf(float x) {
    unsigned u = __float_as_uint(x);
    u += 0x7FFFu + ((u >> 16) & 1u);           // RNE
    return (u16)(u >> 16);
}
__device__ __forceinline__ float bf2f(u16 b) { return __uint_as_float(((unsigned)b) << 16); }
__device__ __forceinline__ void split2(float x, u16& h, u16& l) {
    h = f2bf(x);
    l = f2bf(x - bf2f(h));
}

// async 16B global -> LDS; LDS dest must be linear in lane order
__device__ __forceinline__ void gld16(const u16* g, u16* l) {
    __builtin_amdgcn_global_load_lds(
        (const __attribute__((address_space(1))) void*)g,
        (__attribute__((address_space(3))) void*)l, 16, 0, 0);
}

// vectorized fp32 -> (hi, lo) bf16 split, float4 per thread
__global__ void split4_kernel(const float* __restrict__ x, u16* __restrict__ hi,
                              u16* __restrict__ lo, int n4)
{
    const int stride = gridDim.x * blockDim.x;
    for (int i = blockIdx.x * blockDim.x + threadIdx.x; i < n4; i += stride) {
        const float4 v = ((const float4*)x)[i];
        u16 h0,l0,h1,l1,h2,l2,h3,l3;
        split2(v.x,h0,l0); split2(v.y,h1,l1); split2(v.z,h2,l2); split2(v.w,h3,l3);
        uint2 hp, lp;
        hp.x = (unsigned)h0 | ((unsigned)h1 << 16); hp.y = (unsigned)h2 | ((unsigned)h3 << 16);
        lp.x = (unsigned)l0 | ((unsigned)l1 << 16); lp.y = (unsigned)l2 | ((unsigned)l3 << 16);
        ((uint2*)hi)[i] = hp; ((uint2*)lo)[i] = lp;
    }
}

// vectorized fp32 -> plain bf16 convert (for Whh: recurrence runs pure bf16)
__global__ void cvt4_kernel(const float* __restrict__ x, u16* __restrict__ y, int n4)
{
    const int stride = gridDim.x * blockDim.x;
    for (int i = blockIdx.x * blockDim.x + threadIdx.x; i < n4; i += stride) {
        const float4 v = ((const float4*)x)[i];
        uint2 hp;
        hp.x = (unsigned)f2bf(v.x) | ((unsigned)f2bf(v.y) << 16);
        hp.y = (unsigned)f2bf(v.z) | ((unsigned)f2bf(v.w) << 16);
        ((uint2*)y)[i] = hp;
    }
}

// bcat[0:4096] = bih0+bhh0 ; bcat[4096:8192] = bih1+bhh1
__global__ void bias_cat_kernel(const float* __restrict__ bi0, const float* __restrict__ bh0,
                                const float* __restrict__ bi1, const float* __restrict__ bh1,
                                float* __restrict__ bcat)
{
    const int n = blockIdx.x * blockDim.x + threadIdx.x;
    if (n >= NG) return;
    bcat[n] = (n < G4) ? (bi0[n] + bh0[n]) : (bi1[n - G4] + bh1[n - G4]);
}

// ---------------------------------------------------------------------------
// bf16x3 MFMA GEMM: C[M,N] = A[M,K] @ W[N,K]^T + b1 + b2
// 128x128 tile, BK=32, 256 thr = 4 waves (2x2). W via global_load_lds.
// AFP32: A is fp32, register-staged + split on the fly (saves a split pass).
//  else: A pre-split hi/lo, via global_load_lds.
// Output: EMIT -> split pair (Ch,Cl); else fp32 Cf with NON-TEMPORAL stores
// (G is consumed much later; keep it out of L3 so A/W stay resident).
// 1D grid, bijective XCD swizzle + chunked supertile (cm m-tiles x all n).
// Requires (M/128) % cm == 0, nwg % 8 == 0, K % 32 == 0.
// ---------------------------------------------------------------------------
template<bool AFP32, bool EMIT>
__launch_bounds__(256)
__global__ void mfma_gemm(const float* __restrict__ Af,
                          const u16* __restrict__ Ah, const u16* __restrict__ Al,
                          const u16* __restrict__ Wh, const u16* __restrict__ Wl,
                          const float* __restrict__ b1,
                          float* __restrict__ Cf, u16* __restrict__ Ch, u16* __restrict__ Cl,
                          int M, int N, int K, int cm)
{
    __shared__ u16 sAh[4][128][8]; __shared__ u16 sAl[4][128][8];
    __shared__ u16 sWh[4][128][8]; __shared__ u16 sWl[4][128][8];
    const int tid = threadIdx.x, lane = tid & 63, w = tid >> 6;
    const int wr = w >> 1, wc = w & 1;

    const int nwg = gridDim.x;
    const int cpx = nwg >> 3;
    const int lg = (blockIdx.x & 7) * cpx + (blockIdx.x >> 3);
    const int nby = N >> 7;
    const int cb = cm * nby;
    const int chunk = lg / cb;
    const int r = lg - chunk * cb;
    const int m0 = (chunk * cm + (r % cm)) * 128;
    const int n0 = (r / cm) * 128;

    const u16* Wh0 = Wh + (size_t)n0 * K;
    const u16* Wl0 = Wl + (size_t)n0 * K;

    f32x4 acc[4][4];
#pragma unroll
    for (int i = 0; i < 4; ++i)
#pragma unroll
        for (int j = 0; j < 4; ++j) acc[i][j] = f32x4{0.f, 0.f, 0.f, 0.f};

    const int u1 = tid, u2 = tid + 256;
    const size_t go1 = (size_t)(u1 & 127) * K + (u1 >> 7) * 8;
    const size_t go2 = (size_t)(u2 & 127) * K + (u2 >> 7) * 8;
    u16* const l1 = (u16*)sAh + (size_t)u1 * 8;
    u16* const l2 = (u16*)sAh + (size_t)u2 * 8;
    const size_t dAl = (u16*)sAl - (u16*)sAh;
    const size_t dWh = (u16*)sWh - (u16*)sAh;
    const size_t dWl = (u16*)sWl - (u16*)sAh;

    const float* fa1 = AFP32 ? Af + (size_t)m0 * K + go1 : nullptr;
    const float* fa2 = AFP32 ? Af + (size_t)m0 * K + go2 : nullptr;
    const u16* Ah0 = AFP32 ? nullptr : Ah + (size_t)m0 * K;
    const u16* Al0 = AFP32 ? nullptr : Al + (size_t)m0 * K;

    for (int k0 = 0; k0 < K; k0 += 32) {
        if (AFP32) {
            // register-stage fp32 A, split to hi/lo, ds_write 16B each
            const float4 x0 = *(const float4*)(fa1 + k0);
            const float4 x1 = *(const float4*)(fa1 + k0 + 4);
            const float4 y0 = *(const float4*)(fa2 + k0);
            const float4 y1 = *(const float4*)(fa2 + k0 + 4);
            u16 hb[8], lb[8];
            split2(x0.x,hb[0],lb[0]); split2(x0.y,hb[1],lb[1]);
            split2(x0.z,hb[2],lb[2]); split2(x0.w,hb[3],lb[3]);
            split2(x1.x,hb[4],lb[4]); split2(x1.y,hb[5],lb[5]);
            split2(x1.z,hb[6],lb[6]); split2(x1.w,hb[7],lb[7]);
            *(uint4*)l1 = *(uint4*)hb;
            *(uint4*)(l1 + dAl) = *(uint4*)lb;
            split2(y0.x,hb[0],lb[0]); split2(y0.y,hb[1],lb[1]);
            split2(y0.z,hb[2],lb[2]); split2(y0.w,hb[3],lb[3]);
            split2(y1.x,hb[4],lb[4]); split2(y1.y,hb[5],lb[5]);
            split2(y1.z,hb[6],lb[6]); split2(y1.w,hb[7],lb[7]);
            *(uint4*)l2 = *(uint4*)hb;
            *(uint4*)(l2 + dAl) = *(uint4*)lb;
        } else {
            gld16(Ah0 + go1 + k0, l1);        gld16(Ah0 + go2 + k0, l2);
            gld16(Al0 + go1 + k0, l1 + dAl);  gld16(Al0 + go2 + k0, l2 + dAl);
        }
        gld16(Wh0 + go1 + k0, l1 + dWh);  gld16(Wh0 + go2 + k0, l2 + dWh);
        gld16(Wl0 + go1 + k0, l1 + dWl);  gld16(Wl0 + go2 + k0, l2 + dWl);
        __syncthreads();

        const int kb = lane >> 4, rr = lane & 15;
        short8 Avh[4], Avl[4], Wvh[4], Wvl[4];
#pragma unroll
        for (int i = 0; i < 4; ++i) {
            Avh[i] = *(const short8*)&sAh[kb][wr * 64 + i * 16 + rr][0];
            Avl[i] = *(const short8*)&sAl[kb][wr * 64 + i * 16 + rr][0];
            Wvh[i] = *(const short8*)&sWh[kb][wc * 64 + i * 16 + rr][0];
            Wvl[i] = *(const short8*)&sWl[kb][wc * 64 + i * 16 + rr][0];
        }
#pragma unroll
        for (int i = 0; i < 4; ++i)
#pragma unroll
            for (int j = 0; j < 4; ++j)
                acc[i][j] = __builtin_amdgcn_mfma_f32_16x16x32_bf16(Avh[i], Wvh[j], acc[i][j], 0, 0, 0);
#pragma unroll
        for (int i = 0; i < 4; ++i)
#pragma unroll
            for (int j = 0; j < 4; ++j)
                acc[i][j] = __builtin_amdgcn_mfma_f32_16x16x32_bf16(Avh[i], Wvl[j], acc[i][j], 0, 0, 0);
#pragma unroll
        for (int i = 0; i < 4; ++i)
#pragma unroll
            for (int j = 0; j < 4; ++j)
                acc[i][j] = __builtin_amdgcn_mfma_f32_16x16x32_bf16(Avl[i], Wvh[j], acc[i][j], 0, 0, 0);
        __syncthreads();
    }

    const int rr = lane & 15, rg = lane >> 4;
#pragma unroll
    for (int j = 0; j < 4; ++j) {
        const int col = n0 + wc * 64 + j * 16 + rr;
        const float bias = b1 ? b1[col] : 0.f;
#pragma unroll
        for (int i = 0; i < 4; ++i) {
#pragma unroll
            for (int q = 0; q < 4; ++q) {
                const int row = m0 + wr * 64 + i * 16 + rg * 4 + q;
                const float v = acc[i][j][q] + bias;
                if (EMIT) {
                    u16 h, l; split2(v, h, l);
                    Ch[(size_t)row * N + col] = h;
                    Cl[(size_t)row * N + col] = l;
                } else {
                    __builtin_nontemporal_store(v, &Cf[(size_t)row * N + col]);
                }
            }
        }
    }
}

// ---------------------------------------------------------------------------
// Pure-bf16 MFMA LSTM step: gates = h_in @ Whh^T + G, then cell update.
// Block: 512 threads = 8 waves (4x2), tile 128 batch x (32 j x 4 gates).
// launch_bounds(512,4) -> VGPR<=128 -> 2 blocks/CU (16 waves) for TLP.
// Double-buffered K-loop; G slice loaded non-temporally (read once).
// ---------------------------------------------------------------------------
struct Step2 {
    const u16* Whh[2];     // plain bf16 [4096][1024]
    const float* G[2];     // base + d*G4, row stride NG, row = b*TT + t
    const u16* hin[2];     // [512][1024] bf16
    u16* hout[2];
    float* c[2]; float* hfin[2];
    int t[2];
};

__launch_bounds__(512, 4)
__global__ void lstm_step_bf16(Step2 a, int do_gemm, int write_hfin)
{
    const int l = blockIdx.z;
    __shared__ u16 sA[2][4][128][8];
    __shared__ u16 sW[2][4][128][8];
    const int tid = threadIdx.x, lane = tid & 63, w = tid >> 6;
    const int wr = w >> 1, wc = w & 1;
    const int m0 = blockIdx.x * 128;
    const int j0 = blockIdx.y * 32;

    const u16* __restrict__ hin = a.hin[l];
    const u16* __restrict__ Whh = a.Whh[l];

    f32x4 acc[2][4];
#pragma unroll
    for (int i = 0; i < 2; ++i)
#pragma unroll
        for (int g = 0; g < 4; ++g) acc[i][g] = f32x4{0.f, 0.f, 0.f, 0.f};

    const int rr = lane & 15, rg = lane >> 4;

    if (do_gemm) {
        const int r = tid & 127;
        const size_t goA = (size_t)(m0 + r) * HID + (tid >> 7) * 8;
        const int wrow = ((r >> 4) & 3) * HID + j0 + (r >> 6) * 16 + (r & 15);
        const size_t goW = (size_t)wrow * HID + (tid >> 7) * 8;
        u16* const ldA = (u16*)sA + (size_t)tid * 8;
        u16* const ldW = (u16*)sW + (size_t)tid * 8;

        gld16(hin + goA, ldA);
        gld16(Whh + goW, ldW);
        __syncthreads();

        for (int k0 = 0; k0 < HID; k0 += 32) {
            const int bf = (k0 >> 5) & 1;
            if (k0 + 32 < HID) {
                gld16(hin + goA + k0 + 32, ldA + (bf ^ 1) * 4096);
                gld16(Whh + goW + k0 + 32, ldW + (bf ^ 1) * 4096);
            }
            const int kb = lane >> 4;
            short8 Av[2], Wv[4];
#pragma unroll
            for (int i = 0; i < 2; ++i)
                Av[i] = *(const short8*)&sA[bf][kb][wr * 32 + i * 16 + rr][0];
#pragma unroll
            for (int g = 0; g < 4; ++g)
                Wv[g] = *(const short8*)&sW[bf][kb][wc * 64 + g * 16 + rr][0];
#pragma unroll
            for (int i = 0; i < 2; ++i)
#pragma unroll
                for (int g = 0; g < 4; ++g)
                    acc[i][g] = __builtin_amdgcn_mfma_f32_16x16x32_bf16(Av[i], Wv[g], acc[i][g], 0, 0, 0);
            __syncthreads();
        }
    }

    const int j = j0 + wc * 16 + rr;
    const int t = a.t[l];
    const float* __restrict__ G = a.G[l];
    float* __restrict__ cb = a.c[l];
    float* __restrict__ hf = a.hfin[l];
    u16* __restrict__ ho = a.hout[l];
#pragma unroll
    for (int i = 0; i < 2; ++i) {
#pragma unroll
        for (int q = 0; q < 4; ++q) {
            const int b = m0 + wr * 32 + i * 16 + rg * 4 + q;
            const float* gp = G + ((size_t)b * TT + t) * NG + j;
            const float g0 = __builtin_nontemporal_load(gp);
            const float g1 = __builtin_nontemporal_load(gp + 1024);
            const float g2 = __builtin_nontemporal_load(gp + 2048);
            const float g3 = __builtin_nontemporal_load(gp + 3072);
            const float pi = acc[i][0][q] + g0;
            const float pf = acc[i][1][q] + g1;
            const float pg = acc[i][2][q] + g2;
            const float po = acc[i][3][q] + g3;
            const size_t idx = (size_t)b * HID + j;
            const float cprev = do_gemm ? cb[idx] : 0.f;
            const float cn = sigf(pf) * cprev + sigf(pi) * tanhf(pg);
            cb[idx] = cn;
            const float h = sigf(po) * tanhf(cn);
            if (write_hfin) hf[idx] = h;
            ho[idx] = f2bf(h);
        }
    }
}

// fused[b, n] = prod over streams of concat(h_fwd, h_rev); hfin layout [l][b][j]
__global__ void fuse_mul_kernel(const float* __restrict__ hfin, float* __restrict__ fused)
{
    const int idx = blockIdx.x * blockDim.x + threadIdx.x;
    if (idx >= BATCH * 2 * HID) return;
    const int b = idx >> 11;
    const int n = idx & 2047;
    const int half = n >> 10;
    const int j = n & 1023;
    const size_t o = (size_t)b * HID + j;
    const size_t S = (size_t)BATCH * HID;
    fused[idx] = hfin[(size_t)(0 + half) * S + o] *
                 hfin[(size_t)(2 + half) * S + o] *
                 hfin[(size_t)(4 + half) * S + o];
}

// fp32 vector GEMM for the small classifier (N=200): C = A@W^T + b
__launch_bounds__(256)
__global__ void gemm_bias_kernel(const float* __restrict__ A, const float* __restrict__ W,
                                 const float* __restrict__ b1,
                                 float* __restrict__ C, int M, int N, int K)
{
    __shared__ float As[16][68];
    __shared__ float Ws[16][68];
    const int tid = threadIdx.x;
    const int tx = tid & 15, ty = tid >> 4;
    const int m0 = blockIdx.x * 64;
    const int n0 = blockIdx.y * 64;
    const int lr = tid >> 2;
    const int lk = (tid & 3) << 2;
    const bool mok = (m0 + lr < M);
    const bool nok = (n0 + lr < N);
    const float* Arow = A + (size_t)(m0 + lr) * K + lk;
    const float* Wrow = W + (size_t)(n0 + lr) * K + lk;
    float acc[4][4] = {};

    for (int k0 = 0; k0 < K; k0 += 16) {
        float4 av = make_float4(0.f, 0.f, 0.f, 0.f);
        float4 wv = make_float4(0.f, 0.f, 0.f, 0.f);
        if (mok) av = *(const float4*)(Arow + k0);
        if (nok) wv = *(const float4*)(Wrow + k0);
        As[lk + 0][lr] = av.x; As[lk + 1][lr] = av.y; As[lk + 2][lr] = av.z; As[lk + 3][lr] = av.w;
        Ws[lk + 0][lr] = wv.x; Ws[lk + 1][lr] = wv.y; Ws[lk + 2][lr] = wv.z; Ws[lk + 3][lr] = wv.w;
        __syncthreads();
#pragma unroll
        for (int k = 0; k < 16; ++k) {
            const float4 a = *(const float4*)&As[k][ty << 2];
            const float4 ww = *(const float4*)&Ws[k][tx << 2];
            const float a4[4] = {a.x, a.y, a.z, a.w};
            const float w4[4] = {ww.x, ww.y, ww.z, ww.w};
#pragma unroll
            for (int i = 0; i < 4; ++i)
#pragma unroll
                for (int j = 0; j < 4; ++j)
                    acc[i][j] = fmaf(a4[i], w4[j], acc[i][j]);
        }
        __syncthreads();
    }

#pragma unroll
    for (int i = 0; i < 4; ++i) {
        const int m = m0 + (ty << 2) + i;
        if (m >= M) continue;
#pragma unroll
        for (int j = 0; j < 4; ++j) {
            const int n = n0 + (tx << 2) + j;
            if (n >= N) continue;
            C[(size_t)m * N + n] = acc[i][j] + (b1 ? b1[n] : 0.f);
        }
    }
}

extern "C" void kernel_launch(void* const* d_in, const int* in_sizes, int n_in,
                              void* d_out, int out_size, void* d_ws, size_t ws_size,
                              hipStream_t stream)
{
    const float* resnet   = (const float*)d_in[0];
    const float* c3d      = (const float*)d_in[1];
    const float* audio    = (const float*)d_in[2];
    const float* W_audio  = (const float*)d_in[3];
    const float* b_audio  = (const float*)d_in[4];
    const float* W_resnet = (const float*)d_in[5];
    const float* b_resnet = (const float*)d_in[6];
    const float* W_c3d    = (const float*)d_in[7];
    const float* b_c3d    = (const float*)d_in[8];
    const float* Wih[6]; const float* Whh[6]; const float* bih[6]; const float* bhh[6];
    for (int l = 0; l < 6; ++l) {
        Wih[l] = (const float*)d_in[9 + 4 * l];
        Whh[l] = (const float*)d_in[10 + 4 * l];
        bih[l] = (const float*)d_in[11 + 4 * l];
        bhh[l] = (const float*)d_in[12 + 4 * l];
    }
    const float* W_out = (const float*)d_in[33];
    const float* b_out = (const float*)d_in[34];
    float* out = (float*)d_out;

    const float* feat[3] = { audio, resnet, c3d };
    const float* fb[3]   = { b_audio, b_resnet, b_c3d };
    const int    fK[3]   = { 128, 2048, 4096 };

    // ---- workspace carve (bytes) ----
    char* p = (char*)d_ws;
    char* pend = p + ws_size;
    auto alloc = [&](size_t bytes) -> void* {
        void* q = p; p += (bytes + 255) & ~(size_t)255; return q;
    };
    const size_t FW = (size_t)1024 * (128 + 2048 + 4096);
    u16* fwH   = (u16*)alloc(FW * 2);
    u16* fwL   = (u16*)alloc(FW * 2);
    u16* wihH  = (u16*)alloc((size_t)NG * HID * 2);          // both dirs, d-major
    u16* wihL  = (u16*)alloc((size_t)NG * HID * 2);
    u16* whhB  = (u16*)alloc((size_t)NG * HID * 2);          // plain bf16, d-major
    u16* projH = (u16*)alloc((size_t)BT * HID * 2);
    u16* projL = (u16*)alloc((size_t)BT * HID * 2);
    float* G   = (float*)alloc((size_t)BT * NG * 4);         // merged [BT][8192]
    float* bcat = (float*)alloc((size_t)NG * 4);
    u16* hA    = (u16*)alloc((size_t)2 * BATCH * HID * 2);   // bf16 ping-pong
    u16* hB    = (u16*)alloc((size_t)2 * BATCH * HID * 2);
    float* cb    = (float*)alloc((size_t)2 * BATCH * HID * 4);
    float* hfin  = (float*)alloc((size_t)6 * BATCH * HID * 4);
    float* fused = (float*)alloc((size_t)BATCH * 2 * HID * 4);
    if (p > pend) {
        fprintf(stderr, "kernel_launch: ws too small: need %zu have %zu\n",
                (size_t)(p - (char*)d_ws), ws_size);
        return;
    }

    const dim3 blk(256);
    const size_t fwOff[3] = { 0, (size_t)1024 * 128, (size_t)1024 * 128 + (size_t)1024 * 2048 };
    const size_t S = (size_t)BATCH * HID;

    // split the three projection weight matrices (once)
    for (int st = 0; st < 3; ++st) {
        const int n4 = (1024 * fK[st]) / 4;
        split4_kernel<<<dim3(min(2048, (n4 + 255) / 256)), blk, 0, stream>>>(
            (st == 0 ? W_audio : st == 1 ? W_resnet : W_c3d), fwH + fwOff[st], fwL + fwOff[st], n4);
    }

    for (int st = 0; st < 3; ++st) {
        const int K = fK[st];
        // projection straight from fp32 features (fused split), -> split proj
        mfma_gemm<true, true><<<dim3((BT / 128) * (HID / 128)), blk, 0, stream>>>(
            feat[st], nullptr, nullptr, fwH + fwOff[st], fwL + fwOff[st], fb[st],
            nullptr, projH, projL, BT, HID, K, 16);
        // split Wih / cvt Whh (both directions, d-major contiguous)
        for (int d = 0; d < 2; ++d) {
            const int l = st * 2 + d;
            const size_t woff = (size_t)d * G4 * HID;
            split4_kernel<<<dim3(2048), blk, 0, stream>>>(Wih[l], wihH + woff, wihL + woff, (G4 * HID) / 4);
            cvt4_kernel<<<dim3(2048), blk, 0, stream>>>(Whh[l], whhB + woff, (G4 * HID) / 4);
        }
        // combined bias, merged G GEMM (NT stores): G = proj @ [Wih_f; Wih_r]^T + bcat
        bias_cat_kernel<<<dim3(NG / 256), blk, 0, stream>>>(
            bih[st * 2], bhh[st * 2], bih[st * 2 + 1], bhh[st * 2 + 1], bcat);
        mfma_gemm<false, false><<<dim3((BT / 128) * (NG / 128)), blk, 0, stream>>>(
            nullptr, projH, projL, wihH, wihL, bcat,
            G, nullptr, nullptr, BT, NG, HID, 40);

        for (int s = 0; s < TT; ++s) {
            Step2 a;
            u16* in  = (s & 1) ? hB : hA;
            u16* o   = (s & 1) ? hA : hB;
            for (int d = 0; d < 2; ++d) {
                const int l = st * 2 + d;
                const size_t woff = (size_t)d * G4 * HID;
                const size_t hoff = (size_t)d * BATCH * HID;
                a.Whh[d]  = whhB + woff;
                a.G[d]    = G + (size_t)d * G4;     // column offset in merged layout
                a.hin[d]  = in + hoff;
                a.hout[d] = o + hoff;
                a.c[d]    = cb + hoff;
                a.hfin[d] = hfin + (size_t)l * S;
                a.t[d]    = d ? (TT - 1 - s) : s;
            }
            lstm_step_bf16<<<dim3(BATCH / 128, HID / 32, 2), dim3(512), 0, stream>>>(
                a, s > 0 ? 1 : 0, s == TT - 1 ? 1 : 0);
        }
    }

    // fused elementwise product
    fuse_mul_kernel<<<dim3((BATCH * 2 * HID) / 256), blk, 0, stream>>>(hfin, fused);

    // classifier
    gemm_bias_kernel<<<dim3(BATCH / 64, (NCLS + 63) / 64), blk, 0, stream>>>(
        fused, W_out, b_out, out, BATCH, NCLS, 2 * HID);
}

// Round 9
// 4289.574 us; speedup vs baseline: 1.8148x; 1.2240x over previous
//
#include <hip/hip_runtime.h>
#include <cstdio>
#include <cstdint>

#define TT    20
#define BATCH 512
#define HID   1024
#define G4    4096
#define NG    8192          // both directions' gates, merged
#define BT    (BATCH * TT)  // 10240
#define NCLS  200

typedef unsigned short u16;
typedef __attribute__((ext_vector_type(8))) short short8;   // 8 bf16 (4 VGPRs)
typedef __attribute__((ext_vector_type(4))) float f32x4;

__device__ __forceinline__ float sigf(float x) { return 1.0f / (1.0f + __expf(-x)); }

__device__ __forceinline__ u16 f2bf(float x) {
    unsigned u = __float_as_uint(x);
    u += 0x7FFFu + ((u >> 16) & 1u);           // RNE
    return (u16)(u >> 16);
}
__device__ __forceinline__ float bf2f(u16 b) { return __uint_as_float(((unsigned)b) << 16); }
__device__ __forceinline__ void split2(float x, u16& h, u16& l) {
    h = f2bf(x);
    l = f2bf(x - bf2f(h));
}

// async 16B global -> LDS; LDS dest must be linear in lane order
__device__ __forceinline__ void gld16(const u16* g, u16* l) {
    __builtin_amdgcn_global_load_lds(
        (const __attribute__((address_space(1))) void*)g,
        (__attribute__((address_space(3))) void*)l, 16, 0, 0);
}

// vectorized fp32 -> (hi, lo) bf16 split, float4 per thread
__global__ void split4_kernel(const float* __restrict__ x, u16* __restrict__ hi,
                              u16* __restrict__ lo, int n4)
{
    const int stride = gridDim.x * blockDim.x;
    for (int i = blockIdx.x * blockDim.x + threadIdx.x; i < n4; i += stride) {
        const float4 v = ((const float4*)x)[i];
        u16 h0,l0,h1,l1,h2,l2,h3,l3;
        split2(v.x,h0,l0); split2(v.y,h1,l1); split2(v.z,h2,l2); split2(v.w,h3,l3);
        uint2 hp, lp;
        hp.x = (unsigned)h0 | ((unsigned)h1 << 16); hp.y = (unsigned)h2 | ((unsigned)h3 << 16);
        lp.x = (unsigned)l0 | ((unsigned)l1 << 16); lp.y = (unsigned)l2 | ((unsigned)l3 << 16);
        ((uint2*)hi)[i] = hp; ((uint2*)lo)[i] = lp;
    }
}

// vectorized fp32 -> plain bf16 convert
__global__ void cvt4_kernel(const float* __restrict__ x, u16* __restrict__ y, int n4)
{
    const int stride = gridDim.x * blockDim.x;
    for (int i = blockIdx.x * blockDim.x + threadIdx.x; i < n4; i += stride) {
        const float4 v = ((const float4*)x)[i];
        uint2 hp;
        hp.x = (unsigned)f2bf(v.x) | ((unsigned)f2bf(v.y) << 16);
        hp.y = (unsigned)f2bf(v.z) | ((unsigned)f2bf(v.w) << 16);
        ((uint2*)y)[i] = hp;
    }
}

// bcat[0:4096] = bih0+bhh0 ; bcat[4096:8192] = bih1+bhh1
__global__ void bias_cat_kernel(const float* __restrict__ bi0, const float* __restrict__ bh0,
                                const float* __restrict__ bi1, const float* __restrict__ bh1,
                                float* __restrict__ bcat)
{
    const int n = blockIdx.x * blockDim.x + threadIdx.x;
    if (n >= NG) return;
    bcat[n] = (n < G4) ? (bi0[n] + bh0[n]) : (bi1[n - G4] + bh1[n - G4]);
}

// ---------------------------------------------------------------------------
// bf16x3 proj GEMM: C = A[M,K]fp32 @ Wsplit[N,K]^T + b, emitted as bf16.
// A register-staged + split on the fly; W hi/lo via global_load_lds.
// 128x128 tile, BK=32, 4 waves. XCD swizzle + chunked supertile.
// ---------------------------------------------------------------------------
__launch_bounds__(256)
__global__ void proj_gemm_x3(const float* __restrict__ Af,
                             const u16* __restrict__ Wh, const u16* __restrict__ Wl,
                             const float* __restrict__ b1, u16* __restrict__ Cb,
                             int M, int N, int K, int cm)
{
    __shared__ u16 sAh[4][128][8]; __shared__ u16 sAl[4][128][8];
    __shared__ u16 sWh[4][128][8]; __shared__ u16 sWl[4][128][8];
    const int tid = threadIdx.x, lane = tid & 63, w = tid >> 6;
    const int wr = w >> 1, wc = w & 1;

    const int nwg = gridDim.x;
    const int cpx = nwg >> 3;
    const int lg = (blockIdx.x & 7) * cpx + (blockIdx.x >> 3);
    const int nby = N >> 7;
    const int cb = cm * nby;
    const int chunk = lg / cb;
    const int r = lg - chunk * cb;
    const int m0 = (chunk * cm + (r % cm)) * 128;
    const int n0 = (r / cm) * 128;

    const u16* Wh0 = Wh + (size_t)n0 * K;
    const u16* Wl0 = Wl + (size_t)n0 * K;

    f32x4 acc[4][4];
#pragma unroll
    for (int i = 0; i < 4; ++i)
#pragma unroll
        for (int j = 0; j < 4; ++j) acc[i][j] = f32x4{0.f, 0.f, 0.f, 0.f};

    const int u1 = tid, u2 = tid + 256;
    const size_t go1 = (size_t)(u1 & 127) * K + (u1 >> 7) * 8;
    const size_t go2 = (size_t)(u2 & 127) * K + (u2 >> 7) * 8;
    u16* const l1 = (u16*)sAh + (size_t)u1 * 8;
    u16* const l2 = (u16*)sAh + (size_t)u2 * 8;
    const size_t dAl = (u16*)sAl - (u16*)sAh;
    const size_t dWh = (u16*)sWh - (u16*)sAh;
    const size_t dWl = (u16*)sWl - (u16*)sAh;

    const float* fa1 = Af + (size_t)m0 * K + go1;
    const float* fa2 = Af + (size_t)m0 * K + go2;

    for (int k0 = 0; k0 < K; k0 += 32) {
        {   // register-stage fp32 A, split hi/lo, ds_write 16B each
            const float4 x0 = *(const float4*)(fa1 + k0);
            const float4 x1 = *(const float4*)(fa1 + k0 + 4);
            const float4 y0 = *(const float4*)(fa2 + k0);
            const float4 y1 = *(const float4*)(fa2 + k0 + 4);
            u16 hb[8], lb[8];
            split2(x0.x,hb[0],lb[0]); split2(x0.y,hb[1],lb[1]);
            split2(x0.z,hb[2],lb[2]); split2(x0.w,hb[3],lb[3]);
            split2(x1.x,hb[4],lb[4]); split2(x1.y,hb[5],lb[5]);
            split2(x1.z,hb[6],lb[6]); split2(x1.w,hb[7],lb[7]);
            *(uint4*)l1 = *(uint4*)hb;
            *(uint4*)(l1 + dAl) = *(uint4*)lb;
            split2(y0.x,hb[0],lb[0]); split2(y0.y,hb[1],lb[1]);
            split2(y0.z,hb[2],lb[2]); split2(y0.w,hb[3],lb[3]);
            split2(y1.x,hb[4],lb[4]); split2(y1.y,hb[5],lb[5]);
            split2(y1.z,hb[6],lb[6]); split2(y1.w,hb[7],lb[7]);
            *(uint4*)l2 = *(uint4*)hb;
            *(uint4*)(l2 + dAl) = *(uint4*)lb;
        }
        gld16(Wh0 + go1 + k0, l1 + dWh);  gld16(Wh0 + go2 + k0, l2 + dWh);
        gld16(Wl0 + go1 + k0, l1 + dWl);  gld16(Wl0 + go2 + k0, l2 + dWl);
        __syncthreads();

        const int kb = lane >> 4, rr = lane & 15;
        short8 Avh[4], Avl[4], Wvh[4], Wvl[4];
#pragma unroll
        for (int i = 0; i < 4; ++i) {
            Avh[i] = *(const short8*)&sAh[kb][wr * 64 + i * 16 + rr][0];
            Avl[i] = *(const short8*)&sAl[kb][wr * 64 + i * 16 + rr][0];
            Wvh[i] = *(const short8*)&sWh[kb][wc * 64 + i * 16 + rr][0];
            Wvl[i] = *(const short8*)&sWl[kb][wc * 64 + i * 16 + rr][0];
        }
#pragma unroll
        for (int i = 0; i < 4; ++i)
#pragma unroll
            for (int j = 0; j < 4; ++j)
                acc[i][j] = __builtin_amdgcn_mfma_f32_16x16x32_bf16(Avh[i], Wvh[j], acc[i][j], 0, 0, 0);
#pragma unroll
        for (int i = 0; i < 4; ++i)
#pragma unroll
            for (int j = 0; j < 4; ++j)
                acc[i][j] = __builtin_amdgcn_mfma_f32_16x16x32_bf16(Avh[i], Wvl[j], acc[i][j], 0, 0, 0);
#pragma unroll
        for (int i = 0; i < 4; ++i)
#pragma unroll
            for (int j = 0; j < 4; ++j)
                acc[i][j] = __builtin_amdgcn_mfma_f32_16x16x32_bf16(Avl[i], Wvh[j], acc[i][j], 0, 0, 0);
        __syncthreads();
    }

    const int rr = lane & 15, rg = lane >> 4;
#pragma unroll
    for (int j = 0; j < 4; ++j) {
        const int col = n0 + wc * 64 + j * 16 + rr;
        const float bias = b1 ? b1[col] : 0.f;
#pragma unroll
        for (int i = 0; i < 4; ++i) {
#pragma unroll
            for (int q = 0; q < 4; ++q) {
                const int row = m0 + wr * 64 + i * 16 + rg * 4 + q;
                Cb[(size_t)row * N + col] = f2bf(acc[i][j][q] + bias);
            }
        }
    }
}

// ---------------------------------------------------------------------------
// Pure-bf16 MFMA GEMM (m97 structure): C = A[M,K]bf16 @ W[N,K]bf16^T + b,
// fp32 output with non-temporal stores. 128x128, BK=32, 4 waves,
// global_load_lds staging (8KB A + 8KB W per iter), 16 MFMA/iter.
// ---------------------------------------------------------------------------
__launch_bounds__(256)
__global__ void gemm_b16(const u16* __restrict__ A, const u16* __restrict__ W,
                         const float* __restrict__ b1, float* __restrict__ Cf,
                         int M, int N, int K, int cm)
{
    __shared__ u16 sA[4][128][8]; __shared__ u16 sW[4][128][8];
    const int tid = threadIdx.x, lane = tid & 63, w = tid >> 6;
    const int wr = w >> 1, wc = w & 1;

    const int nwg = gridDim.x;
    const int cpx = nwg >> 3;
    const int lg = (blockIdx.x & 7) * cpx + (blockIdx.x >> 3);
    const int nby = N >> 7;
    const int cb = cm * nby;
    const int chunk = lg / cb;
    const int r = lg - chunk * cb;
    const int m0 = (chunk * cm + (r % cm)) * 128;
    const int n0 = (r / cm) * 128;

    const u16* A0 = A + (size_t)m0 * K;
    const u16* W0 = W + (size_t)n0 * K;

    f32x4 acc[4][4];
#pragma unroll
    for (int i = 0; i < 4; ++i)
#pragma unroll
        for (int j = 0; j < 4; ++j) acc[i][j] = f32x4{0.f, 0.f, 0.f, 0.f};

    const int u1 = tid, u2 = tid + 256;
    const size_t go1 = (size_t)(u1 & 127) * K + (u1 >> 7) * 8;
    const size_t go2 = (size_t)(u2 & 127) * K + (u2 >> 7) * 8;
    u16* const l1 = (u16*)sA + (size_t)u1 * 8;
    u16* const l2 = (u16*)sA + (size_t)u2 * 8;
    const size_t dW = (u16*)sW - (u16*)sA;

    for (int k0 = 0; k0 < K; k0 += 32) {
        gld16(A0 + go1 + k0, l1);       gld16(A0 + go2 + k0, l2);
        gld16(W0 + go1 + k0, l1 + dW);  gld16(W0 + go2 + k0, l2 + dW);
        __syncthreads();

        const int kb = lane >> 4, rr = lane & 15;
        short8 Av[4], Wv[4];
#pragma unroll
        for (int i = 0; i < 4; ++i) {
            Av[i] = *(const short8*)&sA[kb][wr * 64 + i * 16 + rr][0];
            Wv[i] = *(const short8*)&sW[kb][wc * 64 + i * 16 + rr][0];
        }
#pragma unroll
        for (int i = 0; i < 4; ++i)
#pragma unroll
            for (int j = 0; j < 4; ++j)
                acc[i][j] = __builtin_amdgcn_mfma_f32_16x16x32_bf16(Av[i], Wv[j], acc[i][j], 0, 0, 0);
        __syncthreads();
    }

    const int rr = lane & 15, rg = lane >> 4;
#pragma unroll
    for (int j = 0; j < 4; ++j) {
        const int col = n0 + wc * 64 + j * 16 + rr;
        const float bias = b1 ? b1[col] : 0.f;
#pragma unroll
        for (int i = 0; i < 4; ++i) {
#pragma unroll
            for (int q = 0; q < 4; ++q) {
                const int row = m0 + wr * 64 + i * 16 + rg * 4 + q;
                __builtin_nontemporal_store(acc[i][j][q] + bias, &Cf[(size_t)row * N + col]);
            }
        }
    }
}

// ---------------------------------------------------------------------------
// Pure-bf16 MFMA LSTM step (unchanged from R8, validated).
// ---------------------------------------------------------------------------
struct Step2 {
    const u16* Whh[2];     // plain bf16 [4096][1024]
    const float* G[2];     // base + d*G4, row stride NG, row = b*TT + t
    const u16* hin[2];     // [512][1024] bf16
    u16* hout[2];
    float* c[2]; float* hfin[2];
    int t[2];
};

__launch_bounds__(512, 4)
__global__ void lstm_step_bf16(Step2 a, int do_gemm, int write_hfin)
{
    const int l = blockIdx.z;
    __shared__ u16 sA[2][4][128][8];
    __shared__ u16 sW[2][4][128][8];
    const int tid = threadIdx.x, lane = tid & 63, w = tid >> 6;
    const int wr = w >> 1, wc = w & 1;
    const int m0 = blockIdx.x * 128;
    const int j0 = blockIdx.y * 32;

    const u16* __restrict__ hin = a.hin[l];
    const u16* __restrict__ Whh = a.Whh[l];

    f32x4 acc[2][4];
#pragma unroll
    for (int i = 0; i < 2; ++i)
#pragma unroll
        for (int g = 0; g < 4; ++g) acc[i][g] = f32x4{0.f, 0.f, 0.f, 0.f};

    const int rr = lane & 15, rg = lane >> 4;

    if (do_gemm) {
        const int r = tid & 127;
        const size_t goA = (size_t)(m0 + r) * HID + (tid >> 7) * 8;
        const int wrow = ((r >> 4) & 3) * HID + j0 + (r >> 6) * 16 + (r & 15);
        const size_t goW = (size_t)wrow * HID + (tid >> 7) * 8;
        u16* const ldA = (u16*)sA + (size_t)tid * 8;
        u16* const ldW = (u16*)sW + (size_t)tid * 8;

        gld16(hin + goA, ldA);
        gld16(Whh + goW, ldW);
        __syncthreads();

        for (int k0 = 0; k0 < HID; k0 += 32) {
            const int bf = (k0 >> 5) & 1;
            if (k0 + 32 < HID) {
                gld16(hin + goA + k0 + 32, ldA + (bf ^ 1) * 4096);
                gld16(Whh + goW + k0 + 32, ldW + (bf ^ 1) * 4096);
            }
            const int kb = lane >> 4;
            short8 Av[2], Wv[4];
#pragma unroll
            for (int i = 0; i < 2; ++i)
                Av[i] = *(const short8*)&sA[bf][kb][wr * 32 + i * 16 + rr][0];
#pragma unroll
            for (int g = 0; g < 4; ++g)
                Wv[g] = *(const short8*)&sW[bf][kb][wc * 64 + g * 16 + rr][0];
#pragma unroll
            for (int i = 0; i < 2; ++i)
#pragma unroll
                for (int g = 0; g < 4; ++g)
                    acc[i][g] = __builtin_amdgcn_mfma_f32_16x16x32_bf16(Av[i], Wv[g], acc[i][g], 0, 0, 0);
            __syncthreads();
        }
    }

    const int j = j0 + wc * 16 + rr;
    const int t = a.t[l];
    const float* __restrict__ G = a.G[l];
    float* __restrict__ cb = a.c[l];
    float* __restrict__ hf = a.hfin[l];
    u16* __restrict__ ho = a.hout[l];
#pragma unroll
    for (int i = 0; i < 2; ++i) {
#pragma unroll
        for (int q = 0; q < 4; ++q) {
            const int b = m0 + wr * 32 + i * 16 + rg * 4 + q;
            const float* gp = G + ((size_t)b * TT + t) * NG + j;
            const float g0 = __builtin_nontemporal_load(gp);
            const float g1 = __builtin_nontemporal_load(gp + 1024);
            const float g2 = __builtin_nontemporal_load(gp + 2048);
            const float g3 = __builtin_nontemporal_load(gp + 3072);
            const float pi = acc[i][0][q] + g0;
            const float pf = acc[i][1][q] + g1;
            const float pg = acc[i][2][q] + g2;
            const float po = acc[i][3][q] + g3;
            const size_t idx = (size_t)b * HID + j;
            const float cprev = do_gemm ? cb[idx] : 0.f;
            const float cn = sigf(pf) * cprev + sigf(pi) * tanhf(pg);
            cb[idx] = cn;
            const float h = sigf(po) * tanhf(cn);
            if (write_hfin) hf[idx] = h;
            ho[idx] = f2bf(h);
        }
    }
}

// fused[b, n] = prod over streams of concat(h_fwd, h_rev); hfin layout [l][b][j]
__global__ void fuse_mul_kernel(const float* __restrict__ hfin, float* __restrict__ fused)
{
    const int idx = blockIdx.x * blockDim.x + threadIdx.x;
    if (idx >= BATCH * 2 * HID) return;
    const int b = idx >> 11;
    const int n = idx & 2047;
    const int half = n >> 10;
    const int j = n & 1023;
    const size_t o = (size_t)b * HID + j;
    const size_t S = (size_t)BATCH * HID;
    fused[idx] = hfin[(size_t)(0 + half) * S + o] *
                 hfin[(size_t)(2 + half) * S + o] *
                 hfin[(size_t)(4 + half) * S + o];
}

// fp32 vector GEMM for the small classifier (N=200): C = A@W^T + b
__launch_bounds__(256)
__global__ void gemm_bias_kernel(const float* __restrict__ A, const float* __restrict__ W,
                                 const float* __restrict__ b1,
                                 float* __restrict__ C, int M, int N, int K)
{
    __shared__ float As[16][68];
    __shared__ float Ws[16][68];
    const int tid = threadIdx.x;
    const int tx = tid & 15, ty = tid >> 4;
    const int m0 = blockIdx.x * 64;
    const int n0 = blockIdx.y * 64;
    const int lr = tid >> 2;
    const int lk = (tid & 3) << 2;
    const bool mok = (m0 + lr < M);
    const bool nok = (n0 + lr < N);
    const float* Arow = A + (size_t)(m0 + lr) * K + lk;
    const float* Wrow = W + (size_t)(n0 + lr) * K + lk;
    float acc[4][4] = {};

    for (int k0 = 0; k0 < K; k0 += 16) {
        float4 av = make_float4(0.f, 0.f, 0.f, 0.f);
        float4 wv = make_float4(0.f, 0.f, 0.f, 0.f);
        if (mok) av = *(const float4*)(Arow + k0);
        if (nok) wv = *(const float4*)(Wrow + k0);
        As[lk + 0][lr] = av.x; As[lk + 1][lr] = av.y; As[lk + 2][lr] = av.z; As[lk + 3][lr] = av.w;
        Ws[lk + 0][lr] = wv.x; Ws[lk + 1][lr] = wv.y; Ws[lk + 2][lr] = wv.z; Ws[lk + 3][lr] = wv.w;
        __syncthreads();
#pragma unroll
        for (int k = 0; k < 16; ++k) {
            const float4 a = *(const float4*)&As[k][ty << 2];
            const float4 ww = *(const float4*)&Ws[k][tx << 2];
            const float a4[4] = {a.x, a.y, a.z, a.w};
            const float w4[4] = {ww.x, ww.y, ww.z, ww.w};
#pragma unroll
            for (int i = 0; i < 4; ++i)
#pragma unroll
                for (int j = 0; j < 4; ++j)
                    acc[i][j] = fmaf(a4[i], w4[j], acc[i][j]);
        }
        __syncthreads();
    }

#pragma unroll
    for (int i = 0; i < 4; ++i) {
        const int m = m0 + (ty << 2) + i;
        if (m >= M) continue;
#pragma unroll
        for (int j = 0; j < 4; ++j) {
            const int n = n0 + (tx << 2) + j;
            if (n >= N) continue;
            C[(size_t)m * N + n] = acc[i][j] + (b1 ? b1[n] : 0.f);
        }
    }
}

extern "C" void kernel_launch(void* const* d_in, const int* in_sizes, int n_in,
                              void* d_out, int out_size, void* d_ws, size_t ws_size,
                              hipStream_t stream)
{
    const float* resnet   = (const float*)d_in[0];
    const float* c3d      = (const float*)d_in[1];
    const float* audio    = (const float*)d_in[2];
    const float* W_audio  = (const float*)d_in[3];
    const float* b_audio  = (const float*)d_in[4];
    const float* W_resnet = (const float*)d_in[5];
    const float* b_resnet = (const float*)d_in[6];
    const float* W_c3d    = (const float*)d_in[7];
    const float* b_c3d    = (const float*)d_in[8];
    const float* Wih[6]; const float* Whh[6]; const float* bih[6]; const float* bhh[6];
    for (int l = 0; l < 6; ++l) {
        Wih[l] = (const float*)d_in[9 + 4 * l];
        Whh[l] = (const float*)d_in[10 + 4 * l];
        bih[l] = (const float*)d_in[11 + 4 * l];
        bhh[l] = (const float*)d_in[12 + 4 * l];
    }
    const float* W_out = (const float*)d_in[33];
    const float* b_out = (const float*)d_in[34];
    float* out = (float*)d_out;

    const float* feat[3] = { audio, resnet, c3d };
    const float* fb[3]   = { b_audio, b_resnet, b_c3d };
    const int    fK[3]   = { 128, 2048, 4096 };

    // ---- workspace carve (bytes) ----
    char* p = (char*)d_ws;
    char* pend = p + ws_size;
    auto alloc = [&](size_t bytes) -> void* {
        void* q = p; p += (bytes + 255) & ~(size_t)255; return q;
    };
    const size_t FW = (size_t)1024 * (128 + 2048 + 4096);
    u16* fwH   = (u16*)alloc(FW * 2);
    u16* fwL   = (u16*)alloc(FW * 2);
    u16* wihB  = (u16*)alloc((size_t)NG * HID * 2);          // plain bf16, d-major
    u16* whhB  = (u16*)alloc((size_t)NG * HID * 2);          // plain bf16, d-major
    u16* projB = (u16*)alloc((size_t)BT * HID * 2);          // plain bf16
    float* G   = (float*)alloc((size_t)BT * NG * 4);         // merged [BT][8192]
    float* bcat = (float*)alloc((size_t)NG * 4);
    u16* hA    = (u16*)alloc((size_t)2 * BATCH * HID * 2);   // bf16 ping-pong
    u16* hB    = (u16*)alloc((size_t)2 * BATCH * HID * 2);
    float* cb    = (float*)alloc((size_t)2 * BATCH * HID * 4);
    float* hfin  = (float*)alloc((size_t)6 * BATCH * HID * 4);
    float* fused = (float*)alloc((size_t)BATCH * 2 * HID * 4);
    if (p > pend) {
        fprintf(stderr, "kernel_launch: ws too small: need %zu have %zu\n",
                (size_t)(p - (char*)d_ws), ws_size);
        return;
    }

    const dim3 blk(256);
    const size_t fwOff[3] = { 0, (size_t)1024 * 128, (size_t)1024 * 128 + (size_t)1024 * 2048 };
    const size_t S = (size_t)BATCH * HID;

    // split the three projection weight matrices (once; proj stays bf16x3)
    for (int st = 0; st < 3; ++st) {
        const int n4 = (1024 * fK[st]) / 4;
        split4_kernel<<<dim3(min(2048, (n4 + 255) / 256)), blk, 0, stream>>>(
            (st == 0 ? W_audio : st == 1 ? W_resnet : W_c3d), fwH + fwOff[st], fwL + fwOff[st], n4);
    }

    for (int st = 0; st < 3; ++st) {
        const int K = fK[st];
        // projection from fp32 features (bf16x3), emit single-bf16 proj
        proj_gemm_x3<<<dim3((BT / 128) * (HID / 128)), blk, 0, stream>>>(
            feat[st], fwH + fwOff[st], fwL + fwOff[st], fb[st], projB, BT, HID, K, 16);
        // cvt Wih / Whh to plain bf16 (both directions, d-major contiguous)
        for (int d = 0; d < 2; ++d) {
            const int l = st * 2 + d;
            const size_t woff = (size_t)d * G4 * HID;
            cvt4_kernel<<<dim3(2048), blk, 0, stream>>>(Wih[l], wihB + woff, (G4 * HID) / 4);
            cvt4_kernel<<<dim3(2048), blk, 0, stream>>>(Whh[l], whhB + woff, (G4 * HID) / 4);
        }
        // combined bias, merged pure-bf16 G GEMM (NT stores)
        bias_cat_kernel<<<dim3(NG / 256), blk, 0, stream>>>(
            bih[st * 2], bhh[st * 2], bih[st * 2 + 1], bhh[st * 2 + 1], bcat);
        gemm_b16<<<dim3((BT / 128) * (NG / 128)), blk, 0, stream>>>(
            projB, wihB, bcat, G, BT, NG, HID, 40);

        for (int s = 0; s < TT; ++s) {
            Step2 a;
            u16* in  = (s & 1) ? hB : hA;
            u16* o   = (s & 1) ? hA : hB;
            for (int d = 0; d < 2; ++d) {
                const int l = st * 2 + d;
                const size_t woff = (size_t)d * G4 * HID;
                const size_t hoff = (size_t)d * BATCH * HID;
                a.Whh[d]  = whhB + woff;
                a.G[d]    = G + (size_t)d * G4;     // column offset in merged layout
                a.hin[d]  = in + hoff;
                a.hout[d] = o + hoff;
                a.c[d]    = cb + hoff;
                a.hfin[d] = hfin + (size_t)l * S;
                a.t[d]    = d ? (TT - 1 - s) : s;
            }
            lstm_step_bf16<<<dim3(BATCH / 128, HID / 32, 2), dim3(512), 0, stream>>>(
                a, s > 0 ? 1 : 0, s == TT - 1 ? 1 : 0);
        }
    }

    // fused elementwise product
    fuse_mul_kernel<<<dim3((BATCH * 2 * HID) / 256), blk, 0, stream>>>(hfin, fused);

    // classifier
    gemm_bias_kernel<<<dim3(BATCH / 64, (NCLS + 63) / 64), blk, 0, stream>>>(
        fused, W_out, b_out, out, BATCH, NCLS, 2 * HID);
}

// Round 10
// 4026.729 us; speedup vs baseline: 1.9332x; 1.0653x over previous
//
#include <hip/hip_runtime.h>
#include <cstdio>
#include <cstdint>

#define TT    20
#define BATCH 512
#define HID   1024
#define G4    4096
#define NG    8192          // both directions' gates, merged
#define BT    (BATCH * TT)  // 10240
#define NCLS  200

typedef unsigned short u16;
typedef __attribute__((ext_vector_type(8))) short short8;   // 8 bf16 (4 VGPRs)
typedef __attribute__((ext_vector_type(4))) float f32x4;

__device__ __forceinline__ float sigf(float x) { return 1.0f / (1.0f + __expf(-x)); }

__device__ __forceinline__ u16 f2bf(float x) {
    unsigned u = __float_as_uint(x);
    u += 0x7FFFu + ((u >> 16) & 1u);           // RNE
    return (u16)(u >> 16);
}

// async 16B global -> LDS; LDS dest must be linear in lane order
__device__ __forceinline__ void gld16(const u16* g, u16* l) {
    __builtin_amdgcn_global_load_lds(
        (const __attribute__((address_space(1))) void*)g,
        (__attribute__((address_space(3))) void*)l, 16, 0, 0);
}

// vectorized fp32 -> plain bf16 convert
__global__ void cvt4_kernel(const float* __restrict__ x, u16* __restrict__ y, int n4)
{
    const int stride = gridDim.x * blockDim.x;
    for (int i = blockIdx.x * blockDim.x + threadIdx.x; i < n4; i += stride) {
        const float4 v = ((const float4*)x)[i];
        uint2 hp;
        hp.x = (unsigned)f2bf(v.x) | ((unsigned)f2bf(v.y) << 16);
        hp.y = (unsigned)f2bf(v.z) | ((unsigned)f2bf(v.w) << 16);
        ((uint2*)y)[i] = hp;
    }
}

// bcat[0:4096] = bih0+bhh0 ; bcat[4096:8192] = bih1+bhh1
__global__ void bias_cat_kernel(const float* __restrict__ bi0, const float* __restrict__ bh0,
                                const float* __restrict__ bi1, const float* __restrict__ bh1,
                                float* __restrict__ bcat)
{
    const int n = blockIdx.x * blockDim.x + threadIdx.x;
    if (n >= NG) return;
    bcat[n] = (n < G4) ? (bi0[n] + bh0[n]) : (bi1[n - G4] + bh1[n - G4]);
}

// ---------------------------------------------------------------------------
// Pure-bf16 MFMA GEMM (m97 structure): C = A[M,K]bf16 @ W[N,K]bf16^T + b.
// EMITB: write bf16 (proj path); else fp32 with non-temporal stores (G path).
// 128x128, BK=32, 4 waves, global_load_lds staging, 16 MFMA/iter.
// 1D grid, bijective XCD swizzle + chunked supertile (cm m-tiles x all n).
// Requires (M/128) % cm == 0, nwg % 8 == 0, K % 32 == 0.
// ---------------------------------------------------------------------------
template<bool EMITB>
__launch_bounds__(256)
__global__ void gemm_b16(const u16* __restrict__ A, const u16* __restrict__ W,
                         const float* __restrict__ b1, float* __restrict__ Cf,
                         u16* __restrict__ Cb, int M, int N, int K, int cm)
{
    __shared__ u16 sA[4][128][8]; __shared__ u16 sW[4][128][8];
    const int tid = threadIdx.x, lane = tid & 63, w = tid >> 6;
    const int wr = w >> 1, wc = w & 1;

    const int nwg = gridDim.x;
    const int cpx = nwg >> 3;
    const int lg = (blockIdx.x & 7) * cpx + (blockIdx.x >> 3);
    const int nby = N >> 7;
    const int cb = cm * nby;
    const int chunk = lg / cb;
    const int r = lg - chunk * cb;
    const int m0 = (chunk * cm + (r % cm)) * 128;
    const int n0 = (r / cm) * 128;

    const u16* A0 = A + (size_t)m0 * K;
    const u16* W0 = W + (size_t)n0 * K;

    f32x4 acc[4][4];
#pragma unroll
    for (int i = 0; i < 4; ++i)
#pragma unroll
        for (int j = 0; j < 4; ++j) acc[i][j] = f32x4{0.f, 0.f, 0.f, 0.f};

    const int u1 = tid, u2 = tid + 256;
    const size_t go1 = (size_t)(u1 & 127) * K + (u1 >> 7) * 8;
    const size_t go2 = (size_t)(u2 & 127) * K + (u2 >> 7) * 8;
    u16* const l1 = (u16*)sA + (size_t)u1 * 8;
    u16* const l2 = (u16*)sA + (size_t)u2 * 8;
    const size_t dW = (u16*)sW - (u16*)sA;

    for (int k0 = 0; k0 < K; k0 += 32) {
        gld16(A0 + go1 + k0, l1);       gld16(A0 + go2 + k0, l2);
        gld16(W0 + go1 + k0, l1 + dW);  gld16(W0 + go2 + k0, l2 + dW);
        __syncthreads();

        const int kb = lane >> 4, rr = lane & 15;
        short8 Av[4], Wv[4];
#pragma unroll
        for (int i = 0; i < 4; ++i) {
            Av[i] = *(const short8*)&sA[kb][wr * 64 + i * 16 + rr][0];
            Wv[i] = *(const short8*)&sW[kb][wc * 64 + i * 16 + rr][0];
        }
#pragma unroll
        for (int i = 0; i < 4; ++i)
#pragma unroll
            for (int j = 0; j < 4; ++j)
                acc[i][j] = __builtin_amdgcn_mfma_f32_16x16x32_bf16(Av[i], Wv[j], acc[i][j], 0, 0, 0);
        __syncthreads();
    }

    const int rr = lane & 15, rg = lane >> 4;
#pragma unroll
    for (int j = 0; j < 4; ++j) {
        const int col = n0 + wc * 64 + j * 16 + rr;
        const float bias = b1 ? b1[col] : 0.f;
#pragma unroll
        for (int i = 0; i < 4; ++i) {
#pragma unroll
            for (int q = 0; q < 4; ++q) {
                const int row = m0 + wr * 64 + i * 16 + rg * 4 + q;
                const float v = acc[i][j][q] + bias;
                if (EMITB) Cb[(size_t)row * N + col] = f2bf(v);
                else       __builtin_nontemporal_store(v, &Cf[(size_t)row * N + col]);
            }
        }
    }
}

// ---------------------------------------------------------------------------
// Pure-bf16 MFMA LSTM step: gates = h_in @ Whh^T + G, then cell update.
// Block: 256 threads = 4 waves (2x2), tile 64 batch x (32 j x 4 gates).
// Grid (8,32,2) = 512 blocks -> 2 blocks/CU for latency hiding.
// Double-buffered K-loop; W gate-interleaved via per-lane global source
// addresses (LDS stays linear for global_load_lds). Lane owns all 4 gates
// of its (b, j) -> in-register cell update. G non-temporal (read once).
// ---------------------------------------------------------------------------
struct Step2 {
    const u16* Whh[2];     // plain bf16 [4096][1024]
    const float* G[2];     // base + d*G4, row stride NG, row = b*TT + t
    const u16* hin[2];     // [512][1024] bf16
    u16* hout[2];
    float* c[2]; float* hfin[2];
    int t[2];
};

__launch_bounds__(256)
__global__ void lstm_step_bf16(Step2 a, int do_gemm, int write_hfin)
{
    const int l = blockIdx.z;
    __shared__ u16 sA[2][4][64][8];    // 2 x 4 KB
    __shared__ u16 sW[2][4][128][8];   // 2 x 8 KB
    const int tid = threadIdx.x, lane = tid & 63, w = tid >> 6;
    const int wr = w >> 1, wc = w & 1;
    const int m0 = blockIdx.x * 64;
    const int j0 = blockIdx.y * 32;

    const u16* __restrict__ hin = a.hin[l];
    const u16* __restrict__ Whh = a.Whh[l];

    f32x4 acc[2][4];
#pragma unroll
    for (int i = 0; i < 2; ++i)
#pragma unroll
        for (int g = 0; g < 4; ++g) acc[i][g] = f32x4{0.f, 0.f, 0.f, 0.f};

    const int rr = lane & 15, rg = lane >> 4;

    if (do_gemm) {
        // A: 64 rows x 32 k; thread covers row tid&63, chunk tid>>6
        const size_t goA = (size_t)(m0 + (tid & 63)) * HID + (tid >> 6) * 8;
        // W: 128 gate-interleaved rows x 32 k; two gld16 per thread
        const int rW = tid & 127;
        const int wrow = ((rW >> 4) & 3) * HID + j0 + (rW >> 6) * 16 + (rW & 15);
        const size_t goW1 = (size_t)wrow * HID + (tid >> 7) * 8;        // chunks 0-1
        const size_t goW2 = (size_t)wrow * HID + ((tid >> 7) + 2) * 8;  // chunks 2-3
        u16* const ldA  = (u16*)sA + (size_t)tid * 8;
        u16* const ldW1 = (u16*)sW + (size_t)tid * 8;
        u16* const ldW2 = (u16*)sW + (size_t)(tid + 256) * 8;

        gld16(hin + goA,  ldA);
        gld16(Whh + goW1, ldW1);
        gld16(Whh + goW2, ldW2);
        __syncthreads();

        for (int k0 = 0; k0 < HID; k0 += 32) {
            const int bf = (k0 >> 5) & 1;
            if (k0 + 32 < HID) {
                gld16(hin + goA  + k0 + 32, ldA  + (bf ^ 1) * 2048);
                gld16(Whh + goW1 + k0 + 32, ldW1 + (bf ^ 1) * 4096);
                gld16(Whh + goW2 + k0 + 32, ldW2 + (bf ^ 1) * 4096);
            }
            const int kb = lane >> 4;
            short8 Av[2], Wv[4];
#pragma unroll
            for (int i = 0; i < 2; ++i)
                Av[i] = *(const short8*)&sA[bf][kb][wr * 32 + i * 16 + rr][0];
#pragma unroll
            for (int g = 0; g < 4; ++g)
                Wv[g] = *(const short8*)&sW[bf][kb][wc * 64 + g * 16 + rr][0];
#pragma unroll
            for (int i = 0; i < 2; ++i)
#pragma unroll
                for (int g = 0; g < 4; ++g)
                    acc[i][g] = __builtin_amdgcn_mfma_f32_16x16x32_bf16(Av[i], Wv[g], acc[i][g], 0, 0, 0);
            __syncthreads();
        }
    }

    const int j = j0 + wc * 16 + rr;
    const int t = a.t[l];
    const float* __restrict__ G = a.G[l];
    float* __restrict__ cb = a.c[l];
    float* __restrict__ hf = a.hfin[l];
    u16* __restrict__ ho = a.hout[l];
#pragma unroll
    for (int i = 0; i < 2; ++i) {
#pragma unroll
        for (int q = 0; q < 4; ++q) {
            const int b = m0 + wr * 32 + i * 16 + rg * 4 + q;
            const float* gp = G + ((size_t)b * TT + t) * NG + j;
            const float g0 = __builtin_nontemporal_load(gp);
            const float g1 = __builtin_nontemporal_load(gp + 1024);
            const float g2 = __builtin_nontemporal_load(gp + 2048);
            const float g3 = __builtin_nontemporal_load(gp + 3072);
            const float pi = acc[i][0][q] + g0;
            const float pf = acc[i][1][q] + g1;
            const float pg = acc[i][2][q] + g2;
            const float po = acc[i][3][q] + g3;
            const size_t idx = (size_t)b * HID + j;
            const float cprev = do_gemm ? cb[idx] : 0.f;
            const float cn = sigf(pf) * cprev + sigf(pi) * tanhf(pg);
            cb[idx] = cn;
            const float h = sigf(po) * tanhf(cn);
            if (write_hfin) hf[idx] = h;
            ho[idx] = f2bf(h);
        }
    }
}

// fused[b, n] = prod over streams of concat(h_fwd, h_rev); hfin layout [l][b][j]
__global__ void fuse_mul_kernel(const float* __restrict__ hfin, float* __restrict__ fused)
{
    const int idx = blockIdx.x * blockDim.x + threadIdx.x;
    if (idx >= BATCH * 2 * HID) return;
    const int b = idx >> 11;
    const int n = idx & 2047;
    const int half = n >> 10;
    const int j = n & 1023;
    const size_t o = (size_t)b * HID + j;
    const size_t S = (size_t)BATCH * HID;
    fused[idx] = hfin[(size_t)(0 + half) * S + o] *
                 hfin[(size_t)(2 + half) * S + o] *
                 hfin[(size_t)(4 + half) * S + o];
}

// fp32 vector GEMM for the small classifier (N=200): C = A@W^T + b
__launch_bounds__(256)
__global__ void gemm_bias_kernel(const float* __restrict__ A, const float* __restrict__ W,
                                 const float* __restrict__ b1,
                                 float* __restrict__ C, int M, int N, int K)
{
    __shared__ float As[16][68];
    __shared__ float Ws[16][68];
    const int tid = threadIdx.x;
    const int tx = tid & 15, ty = tid >> 4;
    const int m0 = blockIdx.x * 64;
    const int n0 = blockIdx.y * 64;
    const int lr = tid >> 2;
    const int lk = (tid & 3) << 2;
    const bool mok = (m0 + lr < M);
    const bool nok = (n0 + lr < N);
    const float* Arow = A + (size_t)(m0 + lr) * K + lk;
    const float* Wrow = W + (size_t)(n0 + lr) * K + lk;
    float acc[4][4] = {};

    for (int k0 = 0; k0 < K; k0 += 16) {
        float4 av = make_float4(0.f, 0.f, 0.f, 0.f);
        float4 wv = make_float4(0.f, 0.f, 0.f, 0.f);
        if (mok) av = *(const float4*)(Arow + k0);
        if (nok) wv = *(const float4*)(Wrow + k0);
        As[lk + 0][lr] = av.x; As[lk + 1][lr] = av.y; As[lk + 2][lr] = av.z; As[lk + 3][lr] = av.w;
        Ws[lk + 0][lr] = wv.x; Ws[lk + 1][lr] = wv.y; Ws[lk + 2][lr] = wv.z; Ws[lk + 3][lr] = wv.w;
        __syncthreads();
#pragma unroll
        for (int k = 0; k < 16; ++k) {
            const float4 a = *(const float4*)&As[k][ty << 2];
            const float4 ww = *(const float4*)&Ws[k][tx << 2];
            const float a4[4] = {a.x, a.y, a.z, a.w};
            const float w4[4] = {ww.x, ww.y, ww.z, ww.w};
#pragma unroll
            for (int i = 0; i < 4; ++i)
#pragma unroll
                for (int j = 0; j < 4; ++j)
                    acc[i][j] = fmaf(a4[i], w4[j], acc[i][j]);
        }
        __syncthreads();
    }

#pragma unroll
    for (int i = 0; i < 4; ++i) {
        const int m = m0 + (ty << 2) + i;
        if (m >= M) continue;
#pragma unroll
        for (int j = 0; j < 4; ++j) {
            const int n = n0 + (tx << 2) + j;
            if (n >= N) continue;
            C[(size_t)m * N + n] = acc[i][j] + (b1 ? b1[n] : 0.f);
        }
    }
}

extern "C" void kernel_launch(void* const* d_in, const int* in_sizes, int n_in,
                              void* d_out, int out_size, void* d_ws, size_t ws_size,
                              hipStream_t stream)
{
    const float* resnet   = (const float*)d_in[0];
    const float* c3d      = (const float*)d_in[1];
    const float* audio    = (const float*)d_in[2];
    const float* W_audio  = (const float*)d_in[3];
    const float* b_audio  = (const float*)d_in[4];
    const float* W_resnet = (const float*)d_in[5];
    const float* b_resnet = (const float*)d_in[6];
    const float* W_c3d    = (const float*)d_in[7];
    const float* b_c3d    = (const float*)d_in[8];
    const float* Wih[6]; const float* Whh[6]; const float* bih[6]; const float* bhh[6];
    for (int l = 0; l < 6; ++l) {
        Wih[l] = (const float*)d_in[9 + 4 * l];
        Whh[l] = (const float*)d_in[10 + 4 * l];
        bih[l] = (const float*)d_in[11 + 4 * l];
        bhh[l] = (const float*)d_in[12 + 4 * l];
    }
    const float* W_out = (const float*)d_in[33];
    const float* b_out = (const float*)d_in[34];
    float* out = (float*)d_out;

    const float* feat[3] = { audio, resnet, c3d };
    const float* fw[3]   = { W_audio, W_resnet, W_c3d };
    const float* fb[3]   = { b_audio, b_resnet, b_c3d };
    const int    fK[3]   = { 128, 2048, 4096 };

    // ---- workspace carve (bytes) ----
    char* p = (char*)d_ws;
    char* pend = p + ws_size;
    auto alloc = [&](size_t bytes) -> void* {
        void* q = p; p += (bytes + 255) & ~(size_t)255; return q;
    };
    const size_t FW = (size_t)1024 * (128 + 2048 + 4096);
    u16* featB = (u16*)alloc((size_t)BT * 4096 * 2);         // bf16 features (reused)
    u16* fwB   = (u16*)alloc(FW * 2);                        // bf16 proj weights
    u16* wihB  = (u16*)alloc((size_t)NG * HID * 2);          // plain bf16, d-major
    u16* whhB  = (u16*)alloc((size_t)NG * HID * 2);          // plain bf16, d-major
    u16* projB = (u16*)alloc((size_t)BT * HID * 2);          // plain bf16
    float* G   = (float*)alloc((size_t)BT * NG * 4);         // merged [BT][8192]
    float* bcat = (float*)alloc((size_t)NG * 4);
    u16* hA    = (u16*)alloc((size_t)2 * BATCH * HID * 2);   // bf16 ping-pong
    u16* hB    = (u16*)alloc((size_t)2 * BATCH * HID * 2);
    float* cb    = (float*)alloc((size_t)2 * BATCH * HID * 4);
    float* hfin  = (float*)alloc((size_t)6 * BATCH * HID * 4);
    float* fused = (float*)alloc((size_t)BATCH * 2 * HID * 4);
    if (p > pend) {
        fprintf(stderr, "kernel_launch: ws too small: need %zu have %zu\n",
                (size_t)(p - (char*)d_ws), ws_size);
        return;
    }

    const dim3 blk(256);
    const size_t fwOff[3] = { 0, (size_t)1024 * 128, (size_t)1024 * 128 + (size_t)1024 * 2048 };
    const size_t S = (size_t)BATCH * HID;

    // cvt the three projection weight matrices to bf16 (once)
    for (int st = 0; st < 3; ++st) {
        const int n4 = (1024 * fK[st]) / 4;
        cvt4_kernel<<<dim3(min(2048, (n4 + 255) / 256)), blk, 0, stream>>>(
            fw[st], fwB + fwOff[st], n4);
    }

    for (int st = 0; st < 3; ++st) {
        const int K = fK[st];
        // features -> bf16 (single pass)
        cvt4_kernel<<<dim3(2048), blk, 0, stream>>>(feat[st], featB, (BT * K) / 4);
        // projection (pure bf16), emit bf16 proj
        gemm_b16<true><<<dim3((BT / 128) * (HID / 128)), blk, 0, stream>>>(
            featB, fwB + fwOff[st], fb[st], nullptr, projB, BT, HID, K, 16);
        // cvt Wih / Whh to plain bf16 (both directions, d-major contiguous)
        for (int d = 0; d < 2; ++d) {
            const int l = st * 2 + d;
            const size_t woff = (size_t)d * G4 * HID;
            cvt4_kernel<<<dim3(2048), blk, 0, stream>>>(Wih[l], wihB + woff, (G4 * HID) / 4);
            cvt4_kernel<<<dim3(2048), blk, 0, stream>>>(Whh[l], whhB + woff, (G4 * HID) / 4);
        }
        // combined bias, merged pure-bf16 G GEMM (NT stores)
        bias_cat_kernel<<<dim3(NG / 256), blk, 0, stream>>>(
            bih[st * 2], bhh[st * 2], bih[st * 2 + 1], bhh[st * 2 + 1], bcat);
        gemm_b16<false><<<dim3((BT / 128) * (NG / 128)), blk, 0, stream>>>(
            projB, wihB, bcat, G, nullptr, BT, NG, HID, 40);

        for (int s = 0; s < TT; ++s) {
            Step2 a;
            u16* in  = (s & 1) ? hB : hA;
            u16* o   = (s & 1) ? hA : hB;
            for (int d = 0; d < 2; ++d) {
                const int l = st * 2 + d;
                const size_t woff = (size_t)d * G4 * HID;
                const size_t hoff = (size_t)d * BATCH * HID;
                a.Whh[d]  = whhB + woff;
                a.G[d]    = G + (size_t)d * G4;     // column offset in merged layout
                a.hin[d]  = in + hoff;
                a.hout[d] = o + hoff;
                a.c[d]    = cb + hoff;
                a.hfin[d] = hfin + (size_t)l * S;
                a.t[d]    = d ? (TT - 1 - s) : s;
            }
            lstm_step_bf16<<<dim3(BATCH / 64, HID / 32, 2), blk, 0, stream>>>(
                a, s > 0 ? 1 : 0, s == TT - 1 ? 1 : 0);
        }
    }

    // fused elementwise product
    fuse_mul_kernel<<<dim3((BATCH * 2 * HID) / 256), blk, 0, stream>>>(hfin, fused);

    // classifier
    gemm_bias_kernel<<<dim3(BATCH / 64, (NCLS + 63) / 64), blk, 0, stream>>>(
        fused, W_out, b_out, out, BATCH, NCLS, 2 * HID);
}